// Round 11
// baseline (2787.086 us; speedup 1.0000x reference)
//
#include <hip/hip_runtime.h>
#include <hip/hip_fp16.h>

#define BB 256
#define SS 512
#define EE_N 20000
#define NEGLAM -1.442695041f
typedef _Float16 f16;
typedef __attribute__((ext_vector_type(8))) _Float16 half8;
typedef __attribute__((ext_vector_type(4))) _Float16 half4_;
typedef __attribute__((ext_vector_type(2))) _Float16 half2_;
typedef __attribute__((ext_vector_type(4))) float f32x4;

__device__ __forceinline__ float sigm(float x) {
  return __builtin_amdgcn_rcpf(1.0f + __builtin_amdgcn_exp2f(NEGLAM * x));
}
__device__ __forceinline__ float sigm_pre(float s) {
  return __builtin_amdgcn_rcpf(1.0f + __builtin_amdgcn_exp2f(s));
}

// ---------------- K012: fused prep (folds + Ee + wprep + pe) ----------------
// blocks 0..2499: Ee; 2500..3387: folds; 3388..3483: Wfrag; 3484..4733: pe.
__global__ __launch_bounds__(256) void k012_prep(
    const float* ex_emb, const float* skill_emb, const float* response_emb,
    const float* W_time, const float* b_time,
    const float* W_int, const float* b_int,
    const float* W_b2, const float* b_b2,
    const float* W_learn, const float* b_learn,
    const float* W_forget, const float* b_forget,
    const float* W_pred,
    float* Ee, float* Se, float* Re, float* Te, float* cbias,
    float* c_lg, float* c_fg, float* fix_l,
    float* Wcat, float* M_lnb, f16* Wfrag, float* pe) {
  __shared__ float es[8 * 128];
  int blk = blockIdx.x, tid = threadIdx.x;
  if (blk < 2500) {
    *(float4*)&es[tid * 4] = *(const float4*)&ex_emb[(size_t)blk * 1024 + tid * 4];
    __syncthreads();
    int d = tid & 127, rg = tid >> 7;
    float a0 = 0, a1 = 0, a2 = 0, a3 = 0;
    for (int k = 0; k < 128; k++) {
      float w = W_int[k * 128 + d];
      a0 += es[(rg * 4 + 0) * 128 + k] * w;
      a1 += es[(rg * 4 + 1) * 128 + k] * w;
      a2 += es[(rg * 4 + 2) * 128 + k] * w;
      a3 += es[(rg * 4 + 3) * 128 + k] * w;
    }
    Ee[((size_t)blk * 8 + rg * 4 + 0) * 128 + d] = a0;
    Ee[((size_t)blk * 8 + rg * 4 + 1) * 128 + d] = a1;
    Ee[((size_t)blk * 8 + rg * 4 + 2) * 128 + d] = a2;
    Ee[((size_t)blk * 8 + rg * 4 + 3) * 128 + d] = a3;
  } else if (blk < 3388) {
    int b0 = blk - 2500, j = tid;
    if (j < 128) {
      if (b0 < 500) {
        float a = 0.f;
        for (int k = 0; k < 128; k++) a += skill_emb[b0 * 128 + k] * W_int[(128 + k) * 128 + j];
        Se[b0 * 128 + j] = a;
      } else if (b0 < 502) {
        int i = b0 - 500; float a = 0.f;
        for (int k = 0; k < 128; k++) a += response_emb[i * 128 + k] * W_int[(384 + k) * 128 + j];
        Re[i * 128 + j] = a;
      } else if (b0 == 502) {
        float a = 0.f, c = 0.f;
        for (int k = 0; k < 128; k++) {
          float w = W_int[(256 + k) * 128 + j];
          a += W_time[k] * w; c += b_time[k] * w;
        }
        Te[j] = a; cbias[j] = b_int[j] + c;
      } else if (b0 < 503 + 128) {
        int k = b0 - 503;
        Wcat[k * 256 + j]       = NEGLAM * W_learn[(128 + k) * 128 + j];
        Wcat[k * 256 + 128 + j] = NEGLAM * W_forget[(128 + k) * 128 + j];
      } else if (b0 < 631 + 128) {
        int k = b0 - 631; float a = 0.f, c = 0.f;
        for (int m = 0; m < 128; m++) {
          float w = W_b2[k * 128 + m];
          a += w * (W_learn[(257 + m) * 128 + j] + W_learn[(385 + m) * 128 + j]);
          c += w * W_forget[(384 + m) * 128 + j];
        }
        Wcat[(128 + k) * 256 + j] = NEGLAM * a;
        Wcat[(128 + k) * 256 + 128 + j] = NEGLAM * c;
      } else if (b0 < 759 + 128) {
        int k = b0 - 759; float a = 0.f;
        for (int m = 0; m < 128; m++) a += W_b2[k * 128 + m] * W_learn[(385 + m) * 128 + j];
        M_lnb[k * 128 + j] = NEGLAM * a;
      } else {
        float a = 0.f, c = 0.f, f = 0.f;
        for (int m = 0; m < 128; m++) {
          float w = b_b2[m];
          a += w * (W_learn[(257 + m) * 128 + j] + W_learn[(385 + m) * 128 + j]);
          c += w * W_forget[(384 + m) * 128 + j];
          f += w * W_learn[(385 + m) * 128 + j];
        }
        c_lg[j] = NEGLAM * (b_learn[j] + a);
        c_fg[j] = NEGLAM * (b_forget[j] + c);
        fix_l[j] = NEGLAM * f;
      }
    }
  } else if (blk < 3484) {
    int b2 = blk - 3388;                // 0..95 = (mat*8 + w)*4 + t4
    if (tid < 64) {
      int mat = b2 >> 5, rem = b2 & 31, w = rem >> 2, t4 = rem & 3;
      int lane = tid, cc = lane & 15, gg = lane >> 4;
      const float* src = (mat == 0) ? W_learn : (mat == 1 ? W_forget : W_forget + 256 * 128);
      f16* dst = Wfrag + ((size_t)b2 * 64 + lane) * 8;
      #pragma unroll
      for (int e = 0; e < 8; e++) {
        int k = t4 * 32 + gg * 8 + e;
        int j = 16 * w + cc;
        dst[e] = (f16)(NEGLAM * src[k * 128 + j]);
      }
    }
  } else {
    // pe[e] = ex_emb[e] . W_pred[128:256]
    int b3 = blk - 3484;
    int w = tid >> 6, l = tid & 63, g = l >> 4, li = l & 15;
    int row = b3 * 16 + w * 4 + g;
    const float4* ep = (const float4*)(ex_emb + (size_t)row * 128 + li * 8);
    const float4* wp = (const float4*)(W_pred + 128 + li * 8);
    float4 e0 = ep[0], e1 = ep[1], w0 = wp[0], w1 = wp[1];
    float s = e0.x * w0.x + e0.y * w0.y + e0.z * w0.z + e0.w * w0.w
            + e1.x * w1.x + e1.y * w1.y + e1.z * w1.z + e1.w * w1.w;
    #pragma unroll
    for (int m = 1; m < 16; m <<= 1) s += __shfl_xor(s, m);
    if (li == 0) pe[row] = s;
  }
}

// ---------------- K2b: Wcat -> MFMA B-fragment layout (f16) ----------------
__global__ __launch_bounds__(64) void k2b_bprep(const float* Wcat, f16* Bfrag) {
  int blk = blockIdx.x;               // 0..127 = nct*8 + kt
  int nct = blk >> 3, kt = blk & 7;
  int lane = threadIdx.x;
  int cc = lane & 15, gg = lane >> 4;
  f16* dst = Bfrag + ((size_t)blk * 64 + lane) * 8;
  #pragma unroll
  for (int e = 0; e < 8; e++) {
    int k = kt * 32 + gg * 8 + e;
    dst[e] = (f16)Wcat[k * 256 + nct * 16 + cc];
  }
}

// ---------------- K3: fused pre-activation GEMM via MFMA ----------------
// PRE2 layout: [br][t>>1][col][t&1][{L,F}] f16 — 512 elem (1024 B) per t-pair.
__global__ __launch_bounds__(512) void k3_gemm_mfma(
    const int* ex_seq, const int* sk_seq, const int* re_seq,
    const float* time_seq, const float* interval_seq,
    const float* att_seq, const float* hint_seq,
    const float* W_b1, const float* b_b1,
    const float* Wiv,
    const float* Ee, const float* Se, const float* Re,
    const float* Te, const float* cbias,
    const float* c_lg, const float* c_fg,
    const f16* Bfrag, f16* PRE) {
  __shared__ _Float16 Ah[64 * 256];
  __shared__ float ivs[64];
  int tid = threadIdx.x;
  int w = tid >> 6, lane = tid & 63;
  int c = lane & 15, g = lane >> 4;
  int rowbase = blockIdx.x * 64;

  half8 bfr[2][8];
  const half8* bp = (const half8*)Bfrag;
  #pragma unroll
  for (int ncl = 0; ncl < 2; ncl++)
    #pragma unroll
    for (int kt = 0; kt < 8; kt++)
      bfr[ncl][kt] = bp[((size_t)((w * 2 + ncl) * 8 + kt)) * 64 + lane];

  {
    int r = tid & 63, seg = tid >> 6;
    int row = rowbase + r;
    if (seg == 0) ivs[r] = interval_seq[row];
    char* ab = (char*)Ah;
    if (seg < 4) {
      int ex = ex_seq[row], sk = sk_seq[row], rp = re_seq[row];
      float tm = time_seq[row];
      const float4* ee = (const float4*)(Ee + (size_t)ex * 128 + seg * 32);
      const float4* se = (const float4*)(Se + (size_t)sk * 128 + seg * 32);
      const float4* re = (const float4*)(Re + (size_t)rp * 128 + seg * 32);
      const float4* te = (const float4*)(Te + seg * 32);
      const float4* cb = (const float4*)(cbias + seg * 32);
      #pragma unroll
      for (int i8 = 0; i8 < 4; i8++) {
        half8 hv;
        #pragma unroll
        for (int q = 0; q < 2; q++) {
          float4 e4 = ee[i8 * 2 + q], s4 = se[i8 * 2 + q], r4 = re[i8 * 2 + q];
          float4 t4 = te[i8 * 2 + q], c4 = cb[i8 * 2 + q];
          hv[q * 4 + 0] = (_Float16)fmaxf(e4.x + s4.x + tm * t4.x + r4.x + c4.x, 0.f);
          hv[q * 4 + 1] = (_Float16)fmaxf(e4.y + s4.y + tm * t4.y + r4.y + c4.y, 0.f);
          hv[q * 4 + 2] = (_Float16)fmaxf(e4.z + s4.z + tm * t4.z + r4.z + c4.z, 0.f);
          hv[q * 4 + 3] = (_Float16)fmaxf(e4.w + s4.w + tm * t4.w + r4.w + c4.w, 0.f);
        }
        int k0 = seg * 32 + i8 * 8;
        int byte = r * 512 + k0 * 2; byte ^= ((r & 7) << 4);
        *(half8*)(ab + byte) = hv;
      }
    } else {
      int k2b_ = (seg - 4) * 32;
      float at = att_seq[row], hi = hint_seq[row];
      const float4* wa = (const float4*)(W_b1 + k2b_);
      const float4* wh = (const float4*)(W_b1 + 128 + k2b_);
      const float4* bb = (const float4*)(b_b1 + k2b_);
      #pragma unroll
      for (int i8 = 0; i8 < 4; i8++) {
        half8 hv;
        #pragma unroll
        for (int q = 0; q < 2; q++) {
          float4 a4 = wa[i8 * 2 + q], h4 = wh[i8 * 2 + q], b4 = bb[i8 * 2 + q];
          hv[q * 4 + 0] = (_Float16)fmaxf(at * a4.x + hi * h4.x + b4.x, 0.f);
          hv[q * 4 + 1] = (_Float16)fmaxf(at * a4.y + hi * h4.y + b4.y, 0.f);
          hv[q * 4 + 2] = (_Float16)fmaxf(at * a4.z + hi * h4.z + b4.z, 0.f);
          hv[q * 4 + 3] = (_Float16)fmaxf(at * a4.w + hi * h4.w + b4.w, 0.f);
        }
        int k0 = 128 + k2b_ + i8 * 8;
        int byte = r * 512 + k0 * 2; byte ^= ((r & 7) << 4);
        *(half8*)(ab + byte) = hv;
      }
    }
  }
  __syncthreads();

  f32x4 acc[4][2] = {};
  const char* ab = (const char*)Ah;
  #pragma unroll
  for (int kt = 0; kt < 8; kt++) {
    #pragma unroll
    for (int mr = 0; mr < 4; mr++) {
      int byte = (mr * 16 + c) * 512 + kt * 64 + g * 16; byte ^= ((c & 7) << 4);
      half8 a = *(const half8*)(ab + byte);
      acc[mr][0] = __builtin_amdgcn_mfma_f32_16x16x32_f16(a, bfr[0][kt], acc[mr][0], 0, 0, 0);
      acc[mr][1] = __builtin_amdgcn_mfma_f32_16x16x32_f16(a, bfr[1][kt], acc[mr][1], 0, 0, 0);
    }
  }

  bool isL = (w < 4);
  float addc[2], wiv[2];
  int coff[2];
  #pragma unroll
  for (int ncl = 0; ncl < 2; ncl++) {
    int j = w * 32 + ncl * 16 + c;
    if (isL) { addc[ncl] = c_lg[j]; wiv[ncl] = NEGLAM * Wiv[j]; coff[ncl] = j * 4; }
    else     { addc[ncl] = c_fg[j - 128]; wiv[ncl] = 0.f; coff[ncl] = (j - 128) * 4 + 1; }
  }
  #pragma unroll
  for (int mr = 0; mr < 4; mr++) {
    #pragma unroll
    for (int rr = 0; rr < 4; rr++) {
      int rl = mr * 16 + g * 4 + rr;
      int row = rowbase + rl;
      float iv = ivs[rl];
      size_t base = (size_t)(row >> 9) * 131072 + (size_t)((row & 511) >> 1) * 512 + (row & 1) * 2;
      #pragma unroll
      for (int ncl = 0; ncl < 2; ncl++) {
        float v = acc[mr][ncl][rr] + addc[ncl] + iv * wiv[ncl];
        PRE[base + coff[ncl]] = (f16)v;
      }
    }
  }
}

// ---------------- K4: last-step nb fixup (PRE2, L slot of t=511) ----------------
__global__ __launch_bounds__(128) void k4_fix(
    const float* att_seq, const float* hint_seq,
    const float* W_b1, const float* b_b1,
    const float* M_lnb, const float* fix_l, f16* PRE) {
  int b = blockIdx.x, j = threadIdx.x;
  int row = b * SS + (SS - 1);
  __shared__ float rb_s[128];
  float v = att_seq[row] * W_b1[j] + hint_seq[row] * W_b1[128 + j] + b_b1[j];
  rb_s[j] = fmaxf(v, 0.f);
  __syncthreads();
  float a = fix_l[j];
  for (int m = 0; m < 128; m++) a += rb_s[m] * M_lnb[m * 128 + j];
  size_t idx = (size_t)b * 131072 + 255 * 512 + 2 + j * 4;
  PRE[idx] = (f16)((float)PRE[idx] - a);
}

// ---------------- K5: MFMA scan — two skewed 8-wave groups per block ----------
// 8 blocks x 1024 thr. Group gid owns 16 batch rows with round-9 per-wave
// geometry; group B runs one barrier behind so phase-1 issue of one group
// fills the other group's phase-2 latency on the same SIMDs.
#define BAR() asm volatile("s_waitcnt lgkmcnt(0)\n\ts_barrier" ::: "memory")
#define MF(A, B, C) __builtin_amdgcn_mfma_f32_16x16x32_f16(A, B, C, 0, 0, 0)

__global__ __launch_bounds__(1024, 4) void k5_scan_mfma(
    const f16* __restrict__ PRE, const f16* __restrict__ Wfrag,
    f16* __restrict__ h_blk) {
  __shared__ _Float16 AhA[2][2048], AhB[2][2048], Alg[2][2048];
  int tid = threadIdx.x;
  int wave = tid >> 6, lane = tid & 63;
  int gid = wave >> 3, w = wave & 7;
  int c = lane & 15, g = lane >> 4;
  int b = blockIdx.x;

  if (tid < 512) ((float4*)AhA)[tid] = make_float4(0.f, 0.f, 0.f, 0.f);

  half8 bL[4], bFH[4], bFL[4];
  const half8* wp = (const half8*)Wfrag;
  #pragma unroll
  for (int t4 = 0; t4 < 4; t4++) {
    bL [t4] = wp[((0 * 8 + w) * 4 + t4) * 64 + lane];
    bFH[t4] = wp[((1 * 8 + w) * 4 + t4) * 64 + lane];
    bFL[t4] = wp[((2 * 8 + w) * 4 + t4) * 64 + lane];
  }

  int rd[4], wr[4];
  #pragma unroll
  for (int t4 = 0; t4 < 4; t4++) {
    int K8 = 4 * t4 + g;
    rd[t4] = K8 * 256 + (c ^ (K8 & 3)) * 16;
  }
  {
    int F = 16 * w + c;
    int K8w = F >> 3, q = K8w & 3;
    #pragma unroll
    for (int r = 0; r < 4; r++)
      wr[r] = K8w * 256 + ((4 * g + r) ^ q) * 16 + (F & 7) * 2;
  }

  _Float16* ahA = AhA[gid];
  _Float16* ahB = AhB[gid];
  _Float16* alg = Alg[gid];

  int col = 16 * w + c;
  const f16* pr[4]; f16* hb4[4];
  float hstate[4] = {0.f, 0.f, 0.f, 0.f};
  float lgf[4];
  half4_ pA[4][4], pB[4][4];   // [pair][row] banks
  half4_ hb[4];
  #pragma unroll
  for (int r = 0; r < 4; r++) {
    int br = b * 32 + gid * 16 + g * 4 + r;
    pr[r]  = PRE + (size_t)br * 131072 + col * 4;
    hb4[r] = h_blk + (size_t)br * 65536 + col * 4;
  }
  // prologue: pairs 0..3 into bank A (pair stride 1024 B)
  #pragma unroll
  for (int p = 0; p < 4; p++)
    #pragma unroll
    for (int r = 0; r < 4; r++)
      pA[p][r] = *(const half4_*)((const char*)pr[r] + p * 1024);
  __syncthreads();
  if (gid == 1) BAR();   // skew group B by one barrier interval

  const f32x4 Z4 = {0.f, 0.f, 0.f, 0.f};

#define STEPX(SRC, DST, CB, P, PAR, LB, LOFF, I0, I1, TIN, FLUSH, DOINC)         \
  {                                                                              \
    half8 ha[4];                                                                 \
    _Pragma("unroll")                                                            \
    for (int t4 = 0; t4 < 4; t4++)                                               \
      ha[t4] = *(const half8*)((const char*)(SRC) + rd[t4]);                     \
    if (DOINC) {                                                                 \
      _Pragma("unroll")                                                          \
      for (int r = 0; r < 4; r++) pr[r] += 4096;                                 \
    }                                                                            \
    { const int p_ = (I0) >> 2, r_ = (I0) & 3;                                   \
      LB[p_][r_] = *(const half4_*)((const char*)pr[r_] + (LOFF) + p_ * 1024); } \
    { const int p_ = (I1) >> 2, r_ = (I1) & 3;                                   \
      LB[p_][r_] = *(const half4_*)((const char*)pr[r_] + (LOFF) + p_ * 1024); } \
    f32x4 cL, cF;                                                                \
    _Pragma("unroll")                                                            \
    for (int r = 0; r < 4; r++) {                                                \
      cL[r] = (float)CB[P][r][(PAR) * 2];                                        \
      cF[r] = (float)CB[P][r][(PAR) * 2 + 1];                                    \
    }                                                                            \
    __builtin_amdgcn_s_setprio(1);                                               \
    f32x4 aLa = cL, aLb = Z4;                                                    \
    aLa = MF(ha[0], bL[0], aLa);                                                 \
    aLb = MF(ha[2], bL[2], aLb);                                                 \
    aLa = MF(ha[1], bL[1], aLa);                                                 \
    aLb = MF(ha[3], bL[3], aLb);                                                 \
    __builtin_amdgcn_s_setprio(0);                                               \
    _Pragma("unroll")                                                            \
    for (int r = 0; r < 4; r++) {                                                \
      lgf[r] = sigm_pre(aLa[r] + aLb[r]);                                        \
      *(_Float16*)((char*)alg + wr[r]) = (_Float16)lgf[r];                       \
    }                                                                            \
    BAR();                                                                       \
    half8 la[4];                                                                 \
    _Pragma("unroll")                                                            \
    for (int t4 = 0; t4 < 4; t4++)                                               \
      la[t4] = *(const half8*)((const char*)alg + rd[t4]);                       \
    __builtin_amdgcn_s_setprio(1);                                               \
    f32x4 aHa = cF, aHb = Z4;                                                    \
    aHa = MF(ha[0], bFH[0], aHa);                                                \
    aHb = MF(ha[2], bFH[2], aHb);                                                \
    aHa = MF(ha[1], bFH[1], aHa);                                                \
    aHb = MF(ha[3], bFH[3], aHb);                                                \
    aHa = MF(la[0], bFL[0], aHa);                                                \
    aHb = MF(la[2], bFL[2], aHb);                                                \
    aHa = MF(la[1], bFL[1], aHa);                                                \
    aHb = MF(la[3], bFL[3], aHb);                                                \
    __builtin_amdgcn_s_setprio(0);                                               \
    _Pragma("unroll")                                                            \
    for (int r = 0; r < 4; r++) {                                                \
      float fg = sigm_pre(aHa[r] + aHb[r]);                                      \
      float hn = lgf[r] + fg * hstate[r];                                        \
      hstate[r] = hn;                                                            \
      _Float16 hv = (_Float16)hn;                                                \
      *(_Float16*)((char*)(DST) + wr[r]) = hv;                                   \
      hb[r][TIN] = hv;                                                           \
    }                                                                            \
    if ((FLUSH) >= 0) {                                                          \
      _Pragma("unroll")                                                          \
      for (int r = 0; r < 4; r++)                                                \
        *(half4_*)((char*)hb4[r] + (FLUSH)) = hb[r];                             \
    }                                                                            \
    BAR();                                                                       \
  }

  for (int it = 0; it < 32; ++it) {
    STEPX(ahA, ahB, pA, 0, 0, pB, 4096,  0,  1, 0,   -1, 0);
    STEPX(ahB, ahA, pA, 0, 1, pB, 4096,  2,  3, 1,   -1, 0);
    STEPX(ahA, ahB, pA, 1, 0, pB, 4096,  4,  5, 2,   -1, 0);
    STEPX(ahB, ahA, pA, 1, 1, pB, 4096,  6,  7, 3,    0, 0);
    STEPX(ahA, ahB, pA, 2, 0, pB, 4096,  8,  9, 0,   -1, 0);
    STEPX(ahB, ahA, pA, 2, 1, pB, 4096, 10, 11, 1,   -1, 0);
    STEPX(ahA, ahB, pA, 3, 0, pB, 4096, 12, 13, 2,   -1, 0);
    STEPX(ahB, ahA, pA, 3, 1, pB, 4096, 14, 15, 3, 1024, 0);
    STEPX(ahA, ahB, pB, 0, 0, pA, 0,     0,  1, 0,   -1, 1);
    STEPX(ahB, ahA, pB, 0, 1, pA, 0,     2,  3, 1,   -1, 0);
    STEPX(ahA, ahB, pB, 1, 0, pA, 0,     4,  5, 2,   -1, 0);
    STEPX(ahB, ahA, pB, 1, 1, pA, 0,     6,  7, 3, 2048, 0);
    STEPX(ahA, ahB, pB, 2, 0, pA, 0,     8,  9, 0,   -1, 0);
    STEPX(ahB, ahA, pB, 2, 1, pA, 0,    10, 11, 1,   -1, 0);
    STEPX(ahA, ahB, pB, 3, 0, pA, 0,    12, 13, 2,   -1, 0);
    STEPX(ahB, ahA, pB, 3, 1, pA, 0,    14, 15, 3, 3072, 0);
    #pragma unroll
    for (int r = 0; r < 4; r++) hb4[r] += 2048;
  }
#undef STEPX
  if (gid == 0) BAR();   // balance group B's leading barrier
}

// ---------------- K6: prediction dot-products (blocked h layout) ----------------
__global__ __launch_bounds__(256) void k6_pred(
    const f16* h_blk, const int* ex_seq, const float* pe,
    const float* W_pred, const float* b_pred, float* out) {
  int tid = threadIdx.x;
  int wv = tid >> 6, lane = tid & 63;
  int task = blockIdx.x * 4 + wv;        // 0..32767
  int br = task >> 7, t4b = task & 127;
  const f16* hp = h_blk + ((size_t)br * 128 + t4b) * 128 * 4;
  half4_ h0 = *(const half4_*)(hp + lane * 4);
  half4_ h1 = *(const half4_*)(hp + (lane + 64) * 4);
  float w0 = W_pred[lane], w1 = W_pred[lane + 64];
  float s[4];
  #pragma unroll
  for (int q = 0; q < 4; q++) s[q] = (float)h0[q] * w0 + (float)h1[q] * w1;
  #pragma unroll
  for (int m = 1; m < 64; m <<= 1) {
    #pragma unroll
    for (int q = 0; q < 4; q++) s[q] += __shfl_xor(s[q], m);
  }
  if (lane == 0) {
    int4 ex = *(const int4*)(ex_seq + (size_t)br * 512 + t4b * 4);
    float bb = b_pred[0];
    float4 o;
    o.x = sigm(s[0] + pe[ex.x] + bb);
    o.y = sigm(s[1] + pe[ex.y] + bb);
    o.z = sigm(s[2] + pe[ex.z] + bb);
    o.w = sigm(s[3] + pe[ex.w] + bb);
    *(float4*)(out + (size_t)br * 512 + t4b * 4) = o;
  }
}

extern "C" void kernel_launch(void* const* d_in, const int* in_sizes, int n_in,
                              void* d_out, int out_size, void* d_ws, size_t ws_size,
                              hipStream_t stream) {
  const int*   ex_seq   = (const int*)d_in[0];
  const int*   sk_seq   = (const int*)d_in[1];
  const int*   re_seq   = (const int*)d_in[2];
  const float* time_seq = (const float*)d_in[3];
  const float* interval_seq = (const float*)d_in[4];
  const float* att_seq  = (const float*)d_in[5];
  const float* hint_seq = (const float*)d_in[6];
  // d_in[7] q_matrix: unused
  const float* ex_emb   = (const float*)d_in[8];
  const float* sk_emb   = (const float*)d_in[9];
  const float* re_emb   = (const float*)d_in[10];
  const float* W_time   = (const float*)d_in[11];
  const float* b_time   = (const float*)d_in[12];
  const float* W_int    = (const float*)d_in[13];
  const float* b_int    = (const float*)d_in[14];
  const float* W_b1     = (const float*)d_in[15];
  const float* b_b1     = (const float*)d_in[16];
  const float* W_b2     = (const float*)d_in[17];
  const float* b_b2     = (const float*)d_in[18];
  const float* W_learn  = (const float*)d_in[19];
  const float* b_learn  = (const float*)d_in[20];
  const float* W_forget = (const float*)d_in[21];
  const float* b_forget = (const float*)d_in[22];
  const float* W_pred   = (const float*)d_in[23];
  const float* b_pred   = (const float*)d_in[24];

  char* ws = (char*)d_ws;
  float* Ee    = (float*)(ws);              // 10,240,000
  float* Se    = (float*)(ws + 10240000);
  float* Re    = (float*)(ws + 10496000);
  float* Te    = (float*)(ws + 10497024);
  float* cbias = (float*)(ws + 10497536);
  float* c_lg  = (float*)(ws + 10498048);
  float* c_fg  = (float*)(ws + 10498560);
  float* fix_l = (float*)(ws + 10499072);
  float* Wcat  = (float*)(ws + 10499584);   // 262,144
  float* M_lnb = (float*)(ws + 10761728);   // 65,536
  f16*   PRE   = (f16*)  (ws + 10827264);   // 67,108,864  (pair-interleaved PRE2)
  f16*   h_blk = (f16*)  (ws + 77936128);   // 33,554,432 (blocked layout)
  f16*   Wfrag = (f16*)  (ws + 111490560);  // 98,304
  float* pe    = (float*)(ws + 111588864);  // 80,000 -> total 111,668,864
  // aliased scratch:
  f16*   Bfrag = (f16*)  (ws + 77936128);   // aliases h_blk head (dead until k5)

  k012_prep<<<dim3(4734), dim3(256), 0, stream>>>(
      ex_emb, sk_emb, re_emb, W_time, b_time, W_int, b_int, W_b2, b_b2,
      W_learn, b_learn, W_forget, b_forget, W_pred,
      Ee, Se, Re, Te, cbias, c_lg, c_fg, fix_l, Wcat, M_lnb, Wfrag, pe);
  k2b_bprep<<<dim3(128), dim3(64), 0, stream>>>(Wcat, Bfrag);
  k3_gemm_mfma<<<dim3(2048), dim3(512), 0, stream>>>(
      ex_seq, sk_seq, re_seq, time_seq, interval_seq, att_seq, hint_seq,
      W_b1, b_b1, W_learn + 256 * 128, Ee, Se, Re, Te, cbias, c_lg, c_fg, Bfrag, PRE);
  k4_fix<<<dim3(256), dim3(128), 0, stream>>>(
      att_seq, hint_seq, W_b1, b_b1, M_lnb, fix_l, PRE);
  k5_scan_mfma<<<dim3(8), dim3(1024), 0, stream>>>(PRE, Wfrag, h_blk);
  k6_pred<<<dim3(8192), dim3(256), 0, stream>>>(
      h_blk, ex_seq, pe, W_pred, b_pred, (float*)d_out);
}

// Round 12
// 402.239 us; speedup vs baseline: 6.9289x; 6.9289x over previous
//
#include <hip/hip_runtime.h>
#include <hip/hip_fp16.h>

#define BB 256
#define SS 512
#define EE_N 20000
#define NEGLAM -1.442695041f
typedef _Float16 f16;
typedef __attribute__((ext_vector_type(8))) _Float16 half8;
typedef __attribute__((ext_vector_type(4))) _Float16 half4_;
typedef __attribute__((ext_vector_type(2))) _Float16 half2_;
typedef __attribute__((ext_vector_type(4))) float f32x4;

__device__ __forceinline__ float sigm(float x) {
  return __builtin_amdgcn_rcpf(1.0f + __builtin_amdgcn_exp2f(NEGLAM * x));
}
__device__ __forceinline__ float sigm_pre(float s) {
  return __builtin_amdgcn_rcpf(1.0f + __builtin_amdgcn_exp2f(s));
}

// ---------------- K012: fused prep (folds + Ee + wprep + pe + Bfrag) ---------
// blocks 0..2499: Ee; 2500..3387: folds (Bfrag written directly in MFMA
// fragment layout); 3388..3483: Wfrag; 3484..4733: pe.
__global__ __launch_bounds__(256) void k012_prep(
    const float* ex_emb, const float* skill_emb, const float* response_emb,
    const float* W_time, const float* b_time,
    const float* W_int, const float* b_int,
    const float* W_b2, const float* b_b2,
    const float* W_learn, const float* b_learn,
    const float* W_forget, const float* b_forget,
    const float* W_pred,
    float* Ee, float* Se, float* Re, float* Te, float* cbias,
    float* c_lg, float* c_fg, float* fix_l,
    float* M_lnb, f16* Wfrag, float* pe, f16* Bfrag) {
  __shared__ float es[8 * 128];
  int blk = blockIdx.x, tid = threadIdx.x;
  if (blk < 2500) {
    *(float4*)&es[tid * 4] = *(const float4*)&ex_emb[(size_t)blk * 1024 + tid * 4];
    __syncthreads();
    int d = tid & 127, rg = tid >> 7;
    float a0 = 0, a1 = 0, a2 = 0, a3 = 0;
    for (int k = 0; k < 128; k++) {
      float w = W_int[k * 128 + d];
      a0 += es[(rg * 4 + 0) * 128 + k] * w;
      a1 += es[(rg * 4 + 1) * 128 + k] * w;
      a2 += es[(rg * 4 + 2) * 128 + k] * w;
      a3 += es[(rg * 4 + 3) * 128 + k] * w;
    }
    Ee[((size_t)blk * 8 + rg * 4 + 0) * 128 + d] = a0;
    Ee[((size_t)blk * 8 + rg * 4 + 1) * 128 + d] = a1;
    Ee[((size_t)blk * 8 + rg * 4 + 2) * 128 + d] = a2;
    Ee[((size_t)blk * 8 + rg * 4 + 3) * 128 + d] = a3;
  } else if (blk < 3388) {
    int b0 = blk - 2500, j = tid;
    if (j < 128) {
      if (b0 < 500) {
        float a = 0.f;
        for (int k = 0; k < 128; k++) a += skill_emb[b0 * 128 + k] * W_int[(128 + k) * 128 + j];
        Se[b0 * 128 + j] = a;
      } else if (b0 < 502) {
        int i = b0 - 500; float a = 0.f;
        for (int k = 0; k < 128; k++) a += response_emb[i * 128 + k] * W_int[(384 + k) * 128 + j];
        Re[i * 128 + j] = a;
      } else if (b0 == 502) {
        float a = 0.f, c = 0.f;
        for (int k = 0; k < 128; k++) {
          float w = W_int[(256 + k) * 128 + j];
          a += W_time[k] * w; c += b_time[k] * w;
        }
        Te[j] = a; cbias[j] = b_int[j] + c;
      } else if (b0 < 503 + 128) {
        // Wcat row k (k<128): L-cols = W_learn[128+k][:], F-cols = W_forget[128+k][:]
        int k = b0 - 503;
        int kt = k >> 5, gg = (k >> 3) & 3, e = k & 7;
        int nct = j >> 4, cc = j & 15;
        float vL = NEGLAM * W_learn[(128 + k) * 128 + j];
        float vF = NEGLAM * W_forget[(128 + k) * 128 + j];
        Bfrag[((size_t)((nct * 8 + kt) * 64) + gg * 16 + cc) * 8 + e] = (f16)vL;
        Bfrag[((size_t)(((8 + nct) * 8 + kt) * 64) + gg * 16 + cc) * 8 + e] = (f16)vF;
      } else if (b0 < 631 + 128) {
        // Wcat row 128+k2: W_b2-folded gate inputs
        int k2 = b0 - 631; float a = 0.f, c = 0.f;
        for (int m = 0; m < 128; m++) {
          float w = W_b2[k2 * 128 + m];
          a += w * (W_learn[(257 + m) * 128 + j] + W_learn[(385 + m) * 128 + j]);
          c += w * W_forget[(384 + m) * 128 + j];
        }
        int krow = 128 + k2;
        int kt = krow >> 5, gg = (krow >> 3) & 3, e = krow & 7;
        int nct = j >> 4, cc = j & 15;
        Bfrag[((size_t)((nct * 8 + kt) * 64) + gg * 16 + cc) * 8 + e] = (f16)(NEGLAM * a);
        Bfrag[((size_t)(((8 + nct) * 8 + kt) * 64) + gg * 16 + cc) * 8 + e] = (f16)(NEGLAM * c);
      } else if (b0 < 759 + 128) {
        int k = b0 - 759; float a = 0.f;
        for (int m = 0; m < 128; m++) a += W_b2[k * 128 + m] * W_learn[(385 + m) * 128 + j];
        M_lnb[k * 128 + j] = NEGLAM * a;
      } else {
        float a = 0.f, c = 0.f, f = 0.f;
        for (int m = 0; m < 128; m++) {
          float w = b_b2[m];
          a += w * (W_learn[(257 + m) * 128 + j] + W_learn[(385 + m) * 128 + j]);
          c += w * W_forget[(384 + m) * 128 + j];
          f += w * W_learn[(385 + m) * 128 + j];
        }
        c_lg[j] = NEGLAM * (b_learn[j] + a);
        c_fg[j] = NEGLAM * (b_forget[j] + c);
        fix_l[j] = NEGLAM * f;
      }
    }
  } else if (blk < 3484) {
    int b2 = blk - 3388;                // 0..95 = (mat*8 + w)*4 + t4
    if (tid < 64) {
      int mat = b2 >> 5, rem = b2 & 31, w = rem >> 2, t4 = rem & 3;
      int lane = tid, cc = lane & 15, gg = lane >> 4;
      const float* src = (mat == 0) ? W_learn : (mat == 1 ? W_forget : W_forget + 256 * 128);
      f16* dst = Wfrag + ((size_t)b2 * 64 + lane) * 8;
      #pragma unroll
      for (int e = 0; e < 8; e++) {
        int k = t4 * 32 + gg * 8 + e;
        int j = 16 * w + cc;
        dst[e] = (f16)(NEGLAM * src[k * 128 + j]);
      }
    }
  } else {
    // pe[e] = ex_emb[e] . W_pred[128:256]
    int b3 = blk - 3484;
    int w = tid >> 6, l = tid & 63, g = l >> 4, li = l & 15;
    int row = b3 * 16 + w * 4 + g;
    const float4* ep = (const float4*)(ex_emb + (size_t)row * 128 + li * 8);
    const float4* wp = (const float4*)(W_pred + 128 + li * 8);
    float4 e0 = ep[0], e1 = ep[1], w0 = wp[0], w1 = wp[1];
    float s = e0.x * w0.x + e0.y * w0.y + e0.z * w0.z + e0.w * w0.w
            + e1.x * w1.x + e1.y * w1.y + e1.z * w1.z + e1.w * w1.w;
    #pragma unroll
    for (int m = 1; m < 16; m <<= 1) s += __shfl_xor(s, m);
    if (li == 0) pe[row] = s;
  }
}

// ---------------- K3: fused pre-activation GEMM via MFMA ----------------
// PRE2 layout: [br][t>>1][col][t&1][{L,F}] f16 — 512 elem (1024 B) per t-pair.
__global__ __launch_bounds__(512) void k3_gemm_mfma(
    const int* ex_seq, const int* sk_seq, const int* re_seq,
    const float* time_seq, const float* interval_seq,
    const float* att_seq, const float* hint_seq,
    const float* W_b1, const float* b_b1,
    const float* Wiv,
    const float* Ee, const float* Se, const float* Re,
    const float* Te, const float* cbias,
    const float* c_lg, const float* c_fg,
    const f16* Bfrag, f16* PRE) {
  __shared__ _Float16 Ah[64 * 256];
  __shared__ float ivs[64];
  int tid = threadIdx.x;
  int w = tid >> 6, lane = tid & 63;
  int c = lane & 15, g = lane >> 4;
  int rowbase = blockIdx.x * 64;

  half8 bfr[2][8];
  const half8* bp = (const half8*)Bfrag;
  #pragma unroll
  for (int ncl = 0; ncl < 2; ncl++)
    #pragma unroll
    for (int kt = 0; kt < 8; kt++)
      bfr[ncl][kt] = bp[((size_t)((w * 2 + ncl) * 8 + kt)) * 64 + lane];

  {
    int r = tid & 63, seg = tid >> 6;
    int row = rowbase + r;
    if (seg == 0) ivs[r] = interval_seq[row];
    char* ab = (char*)Ah;
    if (seg < 4) {
      int ex = ex_seq[row], sk = sk_seq[row], rp = re_seq[row];
      float tm = time_seq[row];
      const float4* ee = (const float4*)(Ee + (size_t)ex * 128 + seg * 32);
      const float4* se = (const float4*)(Se + (size_t)sk * 128 + seg * 32);
      const float4* re = (const float4*)(Re + (size_t)rp * 128 + seg * 32);
      const float4* te = (const float4*)(Te + seg * 32);
      const float4* cb = (const float4*)(cbias + seg * 32);
      #pragma unroll
      for (int i8 = 0; i8 < 4; i8++) {
        half8 hv;
        #pragma unroll
        for (int q = 0; q < 2; q++) {
          float4 e4 = ee[i8 * 2 + q], s4 = se[i8 * 2 + q], r4 = re[i8 * 2 + q];
          float4 t4 = te[i8 * 2 + q], c4 = cb[i8 * 2 + q];
          hv[q * 4 + 0] = (_Float16)fmaxf(e4.x + s4.x + tm * t4.x + r4.x + c4.x, 0.f);
          hv[q * 4 + 1] = (_Float16)fmaxf(e4.y + s4.y + tm * t4.y + r4.y + c4.y, 0.f);
          hv[q * 4 + 2] = (_Float16)fmaxf(e4.z + s4.z + tm * t4.z + r4.z + c4.z, 0.f);
          hv[q * 4 + 3] = (_Float16)fmaxf(e4.w + s4.w + tm * t4.w + r4.w + c4.w, 0.f);
        }
        int k0 = seg * 32 + i8 * 8;
        int byte = r * 512 + k0 * 2; byte ^= ((r & 7) << 4);
        *(half8*)(ab + byte) = hv;
      }
    } else {
      int k2b_ = (seg - 4) * 32;
      float at = att_seq[row], hi = hint_seq[row];
      const float4* wa = (const float4*)(W_b1 + k2b_);
      const float4* wh = (const float4*)(W_b1 + 128 + k2b_);
      const float4* bb = (const float4*)(b_b1 + k2b_);
      #pragma unroll
      for (int i8 = 0; i8 < 4; i8++) {
        half8 hv;
        #pragma unroll
        for (int q = 0; q < 2; q++) {
          float4 a4 = wa[i8 * 2 + q], h4 = wh[i8 * 2 + q], b4 = bb[i8 * 2 + q];
          hv[q * 4 + 0] = (_Float16)fmaxf(at * a4.x + hi * h4.x + b4.x, 0.f);
          hv[q * 4 + 1] = (_Float16)fmaxf(at * a4.y + hi * h4.y + b4.y, 0.f);
          hv[q * 4 + 2] = (_Float16)fmaxf(at * a4.z + hi * h4.z + b4.z, 0.f);
          hv[q * 4 + 3] = (_Float16)fmaxf(at * a4.w + hi * h4.w + b4.w, 0.f);
        }
        int k0 = 128 + k2b_ + i8 * 8;
        int byte = r * 512 + k0 * 2; byte ^= ((r & 7) << 4);
        *(half8*)(ab + byte) = hv;
      }
    }
  }
  __syncthreads();

  f32x4 acc[4][2] = {};
  const char* ab = (const char*)Ah;
  #pragma unroll
  for (int kt = 0; kt < 8; kt++) {
    #pragma unroll
    for (int mr = 0; mr < 4; mr++) {
      int byte = (mr * 16 + c) * 512 + kt * 64 + g * 16; byte ^= ((c & 7) << 4);
      half8 a = *(const half8*)(ab + byte);
      acc[mr][0] = __builtin_amdgcn_mfma_f32_16x16x32_f16(a, bfr[0][kt], acc[mr][0], 0, 0, 0);
      acc[mr][1] = __builtin_amdgcn_mfma_f32_16x16x32_f16(a, bfr[1][kt], acc[mr][1], 0, 0, 0);
    }
  }

  bool isL = (w < 4);
  float addc[2], wiv[2];
  int coff[2];
  #pragma unroll
  for (int ncl = 0; ncl < 2; ncl++) {
    int j = w * 32 + ncl * 16 + c;
    if (isL) { addc[ncl] = c_lg[j]; wiv[ncl] = NEGLAM * Wiv[j]; coff[ncl] = j * 4; }
    else     { addc[ncl] = c_fg[j - 128]; wiv[ncl] = 0.f; coff[ncl] = (j - 128) * 4 + 1; }
  }
  #pragma unroll
  for (int mr = 0; mr < 4; mr++) {
    #pragma unroll
    for (int rr = 0; rr < 4; rr++) {
      int rl = mr * 16 + g * 4 + rr;
      int row = rowbase + rl;
      float iv = ivs[rl];
      size_t base = (size_t)(row >> 9) * 131072 + (size_t)((row & 511) >> 1) * 512 + (row & 1) * 2;
      #pragma unroll
      for (int ncl = 0; ncl < 2; ncl++) {
        float v = acc[mr][ncl][rr] + addc[ncl] + iv * wiv[ncl];
        PRE[base + coff[ncl]] = (f16)v;
      }
    }
  }
}

// ---------------- K4: last-step nb fixup (PRE2, L slot of t=511) ----------------
__global__ __launch_bounds__(128) void k4_fix(
    const float* att_seq, const float* hint_seq,
    const float* W_b1, const float* b_b1,
    const float* M_lnb, const float* fix_l, f16* PRE) {
  int b = blockIdx.x, j = threadIdx.x;
  int row = b * SS + (SS - 1);
  __shared__ float rb_s[128];
  float v = att_seq[row] * W_b1[j] + hint_seq[row] * W_b1[128 + j] + b_b1[j];
  rb_s[j] = fmaxf(v, 0.f);
  __syncthreads();
  float a = fix_l[j];
  for (int m = 0; m < 128; m++) a += rb_s[m] * M_lnb[m * 128 + j];
  size_t idx = (size_t)b * 131072 + 255 * 512 + 2 + j * 4;
  PRE[idx] = (f16)((float)PRE[idx] - a);
}

// ---------------- K5: MFMA scan (round-9 calibrated schedule) -----------------
// Pair stride = 1024 B; window = 16 steps = 8 pairs = 8192 B (pr += 4096 elem).
#define BAR() asm volatile("s_waitcnt lgkmcnt(0)\n\ts_barrier" ::: "memory")
#define MF(A, B, C) __builtin_amdgcn_mfma_f32_16x16x32_f16(A, B, C, 0, 0, 0)

__global__ __launch_bounds__(512, 2) void k5_scan_mfma(
    const f16* __restrict__ PRE, const f16* __restrict__ Wfrag,
    f16* __restrict__ h_blk) {
  __shared__ _Float16 AhA[2048], AhB[2048], Alg[2048];
  int tid = threadIdx.x;
  int w = tid >> 6, lane = tid & 63;
  int c = lane & 15, g = lane >> 4;
  int b = blockIdx.x;

  if (tid < 256) ((float4*)AhA)[tid] = make_float4(0.f, 0.f, 0.f, 0.f);

  half8 bL[4], bFH[4], bFL[4];
  const half8* wp = (const half8*)Wfrag;
  #pragma unroll
  for (int t4 = 0; t4 < 4; t4++) {
    bL [t4] = wp[((0 * 8 + w) * 4 + t4) * 64 + lane];
    bFH[t4] = wp[((1 * 8 + w) * 4 + t4) * 64 + lane];
    bFL[t4] = wp[((2 * 8 + w) * 4 + t4) * 64 + lane];
  }

  int rd[4], wr[4];
  #pragma unroll
  for (int t4 = 0; t4 < 4; t4++) {
    int K8 = 4 * t4 + g;
    rd[t4] = K8 * 256 + (c ^ (K8 & 3)) * 16;
  }
  {
    int F = 16 * w + c;
    int K8w = F >> 3, q = K8w & 3;
    #pragma unroll
    for (int r = 0; r < 4; r++)
      wr[r] = K8w * 256 + ((4 * g + r) ^ q) * 16 + (F & 7) * 2;
  }

  int col = 16 * w + c;
  const f16* pr[4]; f16* hb4[4];
  float hstate[4] = {0.f, 0.f, 0.f, 0.f};
  float lgf[4];
  half4_ pA[4][4], pB[4][4];   // [pair][row] banks
  half4_ hb[4];
  #pragma unroll
  for (int r = 0; r < 4; r++) {
    int br = b * 16 + g * 4 + r;
    pr[r]  = PRE + (size_t)br * 131072 + col * 4;
    hb4[r] = h_blk + (size_t)br * 65536 + col * 4;
  }
  // prologue: pairs 0..3 into bank A (pair stride 1024 B)
  #pragma unroll
  for (int p = 0; p < 4; p++)
    #pragma unroll
    for (int r = 0; r < 4; r++)
      pA[p][r] = *(const half4_*)((const char*)pr[r] + p * 1024);
  __syncthreads();

  const f32x4 Z4 = {0.f, 0.f, 0.f, 0.f};

#define STEPX(SRC, DST, CB, P, PAR, LB, LOFF, I0, I1, TIN, FLUSH, DOINC)         \
  {                                                                              \
    half8 ha[4];                                                                 \
    _Pragma("unroll")                                                            \
    for (int t4 = 0; t4 < 4; t4++)                                               \
      ha[t4] = *(const half8*)((const char*)(SRC) + rd[t4]);                     \
    if (DOINC) {                                                                 \
      _Pragma("unroll")                                                          \
      for (int r = 0; r < 4; r++) pr[r] += 4096;                                 \
    }                                                                            \
    { const int p_ = (I0) >> 2, r_ = (I0) & 3;                                   \
      LB[p_][r_] = *(const half4_*)((const char*)pr[r_] + (LOFF) + p_ * 1024); } \
    { const int p_ = (I1) >> 2, r_ = (I1) & 3;                                   \
      LB[p_][r_] = *(const half4_*)((const char*)pr[r_] + (LOFF) + p_ * 1024); } \
    f32x4 cL, cF;                                                                \
    _Pragma("unroll")                                                            \
    for (int r = 0; r < 4; r++) {                                                \
      cL[r] = (float)CB[P][r][(PAR) * 2];                                        \
      cF[r] = (float)CB[P][r][(PAR) * 2 + 1];                                    \
    }                                                                            \
    __builtin_amdgcn_s_setprio(1);                                               \
    f32x4 aLa = cL, aLb = Z4;                                                    \
    aLa = MF(ha[0], bL[0], aLa);                                                 \
    aLb = MF(ha[2], bL[2], aLb);                                                 \
    aLa = MF(ha[1], bL[1], aLa);                                                 \
    aLb = MF(ha[3], bL[3], aLb);                                                 \
    __builtin_amdgcn_s_setprio(0);                                               \
    _Pragma("unroll")                                                            \
    for (int r = 0; r < 4; r++) {                                                \
      lgf[r] = sigm_pre(aLa[r] + aLb[r]);                                        \
      *(_Float16*)((char*)Alg + wr[r]) = (_Float16)lgf[r];                       \
    }                                                                            \
    BAR();                                                                       \
    half8 la[4];                                                                 \
    _Pragma("unroll")                                                            \
    for (int t4 = 0; t4 < 4; t4++)                                               \
      la[t4] = *(const half8*)((const char*)Alg + rd[t4]);                       \
    __builtin_amdgcn_s_setprio(1);                                               \
    f32x4 aHa = cF, aHb = Z4;                                                    \
    aHa = MF(ha[0], bFH[0], aHa);                                                \
    aHb = MF(ha[2], bFH[2], aHb);                                                \
    aHa = MF(ha[1], bFH[1], aHa);                                                \
    aHb = MF(ha[3], bFH[3], aHb);                                                \
    aHa = MF(la[0], bFL[0], aHa);                                                \
    aHb = MF(la[2], bFL[2], aHb);                                                \
    aHa = MF(la[1], bFL[1], aHa);                                                \
    aHb = MF(la[3], bFL[3], aHb);                                                \
    __builtin_amdgcn_s_setprio(0);                                               \
    _Pragma("unroll")                                                            \
    for (int r = 0; r < 4; r++) {                                                \
      float fg = sigm_pre(aHa[r] + aHb[r]);                                      \
      float hn = lgf[r] + fg * hstate[r];                                        \
      hstate[r] = hn;                                                            \
      _Float16 hv = (_Float16)hn;                                                \
      *(_Float16*)((char*)(DST) + wr[r]) = hv;                                   \
      hb[r][TIN] = hv;                                                           \
    }                                                                            \
    if ((FLUSH) >= 0) {                                                          \
      _Pragma("unroll")                                                          \
      for (int r = 0; r < 4; r++)                                                \
        *(half4_*)((char*)hb4[r] + (FLUSH)) = hb[r];                             \
    }                                                                            \
    BAR();                                                                       \
  }

  for (int it = 0; it < 32; ++it) {
    STEPX(AhA, AhB, pA, 0, 0, pB, 4096,  0,  1, 0,   -1, 0);
    STEPX(AhB, AhA, pA, 0, 1, pB, 4096,  2,  3, 1,   -1, 0);
    STEPX(AhA, AhB, pA, 1, 0, pB, 4096,  4,  5, 2,   -1, 0);
    STEPX(AhB, AhA, pA, 1, 1, pB, 4096,  6,  7, 3,    0, 0);
    STEPX(AhA, AhB, pA, 2, 0, pB, 4096,  8,  9, 0,   -1, 0);
    STEPX(AhB, AhA, pA, 2, 1, pB, 4096, 10, 11, 1,   -1, 0);
    STEPX(AhA, AhB, pA, 3, 0, pB, 4096, 12, 13, 2,   -1, 0);
    STEPX(AhB, AhA, pA, 3, 1, pB, 4096, 14, 15, 3, 1024, 0);
    STEPX(AhA, AhB, pB, 0, 0, pA, 0,     0,  1, 0,   -1, 1);
    STEPX(AhB, AhA, pB, 0, 1, pA, 0,     2,  3, 1,   -1, 0);
    STEPX(AhA, AhB, pB, 1, 0, pA, 0,     4,  5, 2,   -1, 0);
    STEPX(AhB, AhA, pB, 1, 1, pA, 0,     6,  7, 3, 2048, 0);
    STEPX(AhA, AhB, pB, 2, 0, pA, 0,     8,  9, 0,   -1, 0);
    STEPX(AhB, AhA, pB, 2, 1, pA, 0,    10, 11, 1,   -1, 0);
    STEPX(AhA, AhB, pB, 3, 0, pA, 0,    12, 13, 2,   -1, 0);
    STEPX(AhB, AhA, pB, 3, 1, pA, 0,    14, 15, 3, 3072, 0);
    #pragma unroll
    for (int r = 0; r < 4; r++) hb4[r] += 2048;
  }
#undef STEPX
}

// ---------------- K6: prediction dot-products (blocked h layout) ----------------
__global__ __launch_bounds__(256) void k6_pred(
    const f16* h_blk, const int* ex_seq, const float* pe,
    const float* W_pred, const float* b_pred, float* out) {
  int tid = threadIdx.x;
  int wv = tid >> 6, lane = tid & 63;
  int task = blockIdx.x * 4 + wv;        // 0..32767
  int br = task >> 7, t4b = task & 127;
  const f16* hp = h_blk + ((size_t)br * 128 + t4b) * 128 * 4;
  half4_ h0 = *(const half4_*)(hp + lane * 4);
  half4_ h1 = *(const half4_*)(hp + (lane + 64) * 4);
  float w0 = W_pred[lane], w1 = W_pred[lane + 64];
  float s[4];
  #pragma unroll
  for (int q = 0; q < 4; q++) s[q] = (float)h0[q] * w0 + (float)h1[q] * w1;
  #pragma unroll
  for (int m = 1; m < 64; m <<= 1) {
    #pragma unroll
    for (int q = 0; q < 4; q++) s[q] += __shfl_xor(s[q], m);
  }
  if (lane == 0) {
    int4 ex = *(const int4*)(ex_seq + (size_t)br * 512 + t4b * 4);
    float bb = b_pred[0];
    float4 o;
    o.x = sigm(s[0] + pe[ex.x] + bb);
    o.y = sigm(s[1] + pe[ex.y] + bb);
    o.z = sigm(s[2] + pe[ex.z] + bb);
    o.w = sigm(s[3] + pe[ex.w] + bb);
    *(float4*)(out + (size_t)br * 512 + t4b * 4) = o;
  }
}

extern "C" void kernel_launch(void* const* d_in, const int* in_sizes, int n_in,
                              void* d_out, int out_size, void* d_ws, size_t ws_size,
                              hipStream_t stream) {
  const int*   ex_seq   = (const int*)d_in[0];
  const int*   sk_seq   = (const int*)d_in[1];
  const int*   re_seq   = (const int*)d_in[2];
  const float* time_seq = (const float*)d_in[3];
  const float* interval_seq = (const float*)d_in[4];
  const float* att_seq  = (const float*)d_in[5];
  const float* hint_seq = (const float*)d_in[6];
  // d_in[7] q_matrix: unused
  const float* ex_emb   = (const float*)d_in[8];
  const float* sk_emb   = (const float*)d_in[9];
  const float* re_emb   = (const float*)d_in[10];
  const float* W_time   = (const float*)d_in[11];
  const float* b_time   = (const float*)d_in[12];
  const float* W_int    = (const float*)d_in[13];
  const float* b_int    = (const float*)d_in[14];
  const float* W_b1     = (const float*)d_in[15];
  const float* b_b1     = (const float*)d_in[16];
  const float* W_b2     = (const float*)d_in[17];
  const float* b_b2     = (const float*)d_in[18];
  const float* W_learn  = (const float*)d_in[19];
  const float* b_learn  = (const float*)d_in[20];
  const float* W_forget = (const float*)d_in[21];
  const float* b_forget = (const float*)d_in[22];
  const float* W_pred   = (const float*)d_in[23];
  const float* b_pred   = (const float*)d_in[24];

  char* ws = (char*)d_ws;
  float* Ee    = (float*)(ws);              // 10,240,000
  float* Se    = (float*)(ws + 10240000);
  float* Re    = (float*)(ws + 10496000);
  float* Te    = (float*)(ws + 10497024);
  float* cbias = (float*)(ws + 10497536);
  float* c_lg  = (float*)(ws + 10498048);
  float* c_fg  = (float*)(ws + 10498560);
  float* fix_l = (float*)(ws + 10499072);
  float* M_lnb = (float*)(ws + 10761728);   // 65,536
  f16*   PRE   = (f16*)  (ws + 10827264);   // 67,108,864  (pair-interleaved PRE2)
  f16*   h_blk = (f16*)  (ws + 77936128);   // 33,554,432 (blocked layout)
  f16*   Wfrag = (f16*)  (ws + 111490560);  // 98,304
  float* pe    = (float*)(ws + 111588864);  // 80,000 -> total 111,668,864
  // aliased scratch:
  f16*   Bfrag = (f16*)  (ws + 77936128);   // aliases h_blk head (dead until k5)

  k012_prep<<<dim3(4734), dim3(256), 0, stream>>>(
      ex_emb, sk_emb, re_emb, W_time, b_time, W_int, b_int, W_b2, b_b2,
      W_learn, b_learn, W_forget, b_forget, W_pred,
      Ee, Se, Re, Te, cbias, c_lg, c_fg, fix_l, M_lnb, Wfrag, pe, Bfrag);
  k3_gemm_mfma<<<dim3(2048), dim3(512), 0, stream>>>(
      ex_seq, sk_seq, re_seq, time_seq, interval_seq, att_seq, hint_seq,
      W_b1, b_b1, W_learn + 256 * 128, Ee, Se, Re, Te, cbias, c_lg, c_fg, Bfrag, PRE);
  k4_fix<<<dim3(256), dim3(128), 0, stream>>>(
      att_seq, hint_seq, W_b1, b_b1, M_lnb, fix_l, PRE);
  k5_scan_mfma<<<dim3(16), dim3(512), 0, stream>>>(PRE, Wfrag, h_blk);
  k6_pred<<<dim3(8192), dim3(256), 0, stream>>>(
      h_blk, ex_seq, pe, W_pred, b_pred, (float*)d_out);
}

// Round 13
// 328.347 us; speedup vs baseline: 8.4882x; 1.2250x over previous
//
#include <hip/hip_runtime.h>
#include <hip/hip_fp16.h>

#define BB 256
#define SS 512
#define EE_N 20000
#define NEGLAM -1.442695041f
typedef _Float16 f16;
typedef __attribute__((ext_vector_type(8))) _Float16 half8;
typedef __attribute__((ext_vector_type(4))) _Float16 half4_;
typedef __attribute__((ext_vector_type(2))) _Float16 half2_;
typedef __attribute__((ext_vector_type(4))) float f32x4;

__device__ __forceinline__ float sigm(float x) {
  return __builtin_amdgcn_rcpf(1.0f + __builtin_amdgcn_exp2f(NEGLAM * x));
}
__device__ __forceinline__ float sigm_pre(float s) {
  return __builtin_amdgcn_rcpf(1.0f + __builtin_amdgcn_exp2f(s));
}

// ---------------- K012: fused prep (folds + Ee + wprep + pe + Bfrag) ---------
__global__ __launch_bounds__(256) void k012_prep(
    const float* ex_emb, const float* skill_emb, const float* response_emb,
    const float* W_time, const float* b_time,
    const float* W_int, const float* b_int,
    const float* W_b2, const float* b_b2,
    const float* W_learn, const float* b_learn,
    const float* W_forget, const float* b_forget,
    const float* W_pred,
    float* Ee, float* Se, float* Re, float* Te, float* cbias,
    float* c_lg, float* c_fg, float* fix_l,
    float* M_lnb, f16* Wfrag, float* pe, f16* Bfrag) {
  __shared__ float es[8 * 128];
  int blk = blockIdx.x, tid = threadIdx.x;
  if (blk < 2500) {
    *(float4*)&es[tid * 4] = *(const float4*)&ex_emb[(size_t)blk * 1024 + tid * 4];
    __syncthreads();
    int d = tid & 127, rg = tid >> 7;
    float a0 = 0, a1 = 0, a2 = 0, a3 = 0;
    for (int k = 0; k < 128; k++) {
      float w = W_int[k * 128 + d];
      a0 += es[(rg * 4 + 0) * 128 + k] * w;
      a1 += es[(rg * 4 + 1) * 128 + k] * w;
      a2 += es[(rg * 4 + 2) * 128 + k] * w;
      a3 += es[(rg * 4 + 3) * 128 + k] * w;
    }
    Ee[((size_t)blk * 8 + rg * 4 + 0) * 128 + d] = a0;
    Ee[((size_t)blk * 8 + rg * 4 + 1) * 128 + d] = a1;
    Ee[((size_t)blk * 8 + rg * 4 + 2) * 128 + d] = a2;
    Ee[((size_t)blk * 8 + rg * 4 + 3) * 128 + d] = a3;
  } else if (blk < 3388) {
    int b0 = blk - 2500, j = tid;
    if (j < 128) {
      if (b0 < 500) {
        float a = 0.f;
        for (int k = 0; k < 128; k++) a += skill_emb[b0 * 128 + k] * W_int[(128 + k) * 128 + j];
        Se[b0 * 128 + j] = a;
      } else if (b0 < 502) {
        int i = b0 - 500; float a = 0.f;
        for (int k = 0; k < 128; k++) a += response_emb[i * 128 + k] * W_int[(384 + k) * 128 + j];
        Re[i * 128 + j] = a;
      } else if (b0 == 502) {
        float a = 0.f, c = 0.f;
        for (int k = 0; k < 128; k++) {
          float w = W_int[(256 + k) * 128 + j];
          a += W_time[k] * w; c += b_time[k] * w;
        }
        Te[j] = a; cbias[j] = b_int[j] + c;
      } else if (b0 < 503 + 128) {
        int k = b0 - 503;
        int kt = k >> 5, gg = (k >> 3) & 3, e = k & 7;
        int nct = j >> 4, cc = j & 15;
        float vL = NEGLAM * W_learn[(128 + k) * 128 + j];
        float vF = NEGLAM * W_forget[(128 + k) * 128 + j];
        Bfrag[((size_t)((nct * 8 + kt) * 64) + gg * 16 + cc) * 8 + e] = (f16)vL;
        Bfrag[((size_t)(((8 + nct) * 8 + kt) * 64) + gg * 16 + cc) * 8 + e] = (f16)vF;
      } else if (b0 < 631 + 128) {
        int k2 = b0 - 631; float a = 0.f, c = 0.f;
        for (int m = 0; m < 128; m++) {
          float w = W_b2[k2 * 128 + m];
          a += w * (W_learn[(257 + m) * 128 + j] + W_learn[(385 + m) * 128 + j]);
          c += w * W_forget[(384 + m) * 128 + j];
        }
        int krow = 128 + k2;
        int kt = krow >> 5, gg = (krow >> 3) & 3, e = krow & 7;
        int nct = j >> 4, cc = j & 15;
        Bfrag[((size_t)((nct * 8 + kt) * 64) + gg * 16 + cc) * 8 + e] = (f16)(NEGLAM * a);
        Bfrag[((size_t)(((8 + nct) * 8 + kt) * 64) + gg * 16 + cc) * 8 + e] = (f16)(NEGLAM * c);
      } else if (b0 < 759 + 128) {
        int k = b0 - 759; float a = 0.f;
        for (int m = 0; m < 128; m++) a += W_b2[k * 128 + m] * W_learn[(385 + m) * 128 + j];
        M_lnb[k * 128 + j] = NEGLAM * a;
      } else {
        float a = 0.f, c = 0.f, f = 0.f;
        for (int m = 0; m < 128; m++) {
          float w = b_b2[m];
          a += w * (W_learn[(257 + m) * 128 + j] + W_learn[(385 + m) * 128 + j]);
          c += w * W_forget[(384 + m) * 128 + j];
          f += w * W_learn[(385 + m) * 128 + j];
        }
        c_lg[j] = NEGLAM * (b_learn[j] + a);
        c_fg[j] = NEGLAM * (b_forget[j] + c);
        fix_l[j] = NEGLAM * f;
      }
    }
  } else if (blk < 3484) {
    int b2 = blk - 3388;                // 0..95 = (mat*8 + w)*4 + t4
    if (tid < 64) {
      int mat = b2 >> 5, rem = b2 & 31, w = rem >> 2, t4 = rem & 3;
      int lane = tid, cc = lane & 15, gg = lane >> 4;
      const float* src = (mat == 0) ? W_learn : (mat == 1 ? W_forget : W_forget + 256 * 128);
      f16* dst = Wfrag + ((size_t)b2 * 64 + lane) * 8;
      #pragma unroll
      for (int e = 0; e < 8; e++) {
        int k = t4 * 32 + gg * 8 + e;
        int j = 16 * w + cc;
        dst[e] = (f16)(NEGLAM * src[k * 128 + j]);
      }
    }
  } else {
    int b3 = blk - 3484;
    int w = tid >> 6, l = tid & 63, g = l >> 4, li = l & 15;
    int row = b3 * 16 + w * 4 + g;
    const float4* ep = (const float4*)(ex_emb + (size_t)row * 128 + li * 8);
    const float4* wp = (const float4*)(W_pred + 128 + li * 8);
    float4 e0 = ep[0], e1 = ep[1], w0 = wp[0], w1 = wp[1];
    float s = e0.x * w0.x + e0.y * w0.y + e0.z * w0.z + e0.w * w0.w
            + e1.x * w1.x + e1.y * w1.y + e1.z * w1.z + e1.w * w1.w;
    #pragma unroll
    for (int m = 1; m < 16; m <<= 1) s += __shfl_xor(s, m);
    if (li == 0) pe[row] = s;
  }
}

// ---------------- K3: fused pre-activation GEMM via MFMA ----------------
// PRE2 layout: [br][t>>1][col][t&1][{L,F}] f16 — 512 elem (1024 B) per t-pair.
__global__ __launch_bounds__(512) void k3_gemm_mfma(
    const int* ex_seq, const int* sk_seq, const int* re_seq,
    const float* time_seq, const float* interval_seq,
    const float* att_seq, const float* hint_seq,
    const float* W_b1, const float* b_b1,
    const float* Wiv,
    const float* Ee, const float* Se, const float* Re,
    const float* Te, const float* cbias,
    const float* c_lg, const float* c_fg,
    const f16* Bfrag, f16* PRE) {
  __shared__ _Float16 Ah[64 * 256];
  __shared__ float ivs[64];
  int tid = threadIdx.x;
  int w = tid >> 6, lane = tid & 63;
  int c = lane & 15, g = lane >> 4;
  int rowbase = blockIdx.x * 64;

  half8 bfr[2][8];
  const half8* bp = (const half8*)Bfrag;
  #pragma unroll
  for (int ncl = 0; ncl < 2; ncl++)
    #pragma unroll
    for (int kt = 0; kt < 8; kt++)
      bfr[ncl][kt] = bp[((size_t)((w * 2 + ncl) * 8 + kt)) * 64 + lane];

  {
    int r = tid & 63, seg = tid >> 6;
    int row = rowbase + r;
    if (seg == 0) ivs[r] = interval_seq[row];
    char* ab = (char*)Ah;
    if (seg < 4) {
      int ex = ex_seq[row], sk = sk_seq[row], rp = re_seq[row];
      float tm = time_seq[row];
      const float4* ee = (const float4*)(Ee + (size_t)ex * 128 + seg * 32);
      const float4* se = (const float4*)(Se + (size_t)sk * 128 + seg * 32);
      const float4* re = (const float4*)(Re + (size_t)rp * 128 + seg * 32);
      const float4* te = (const float4*)(Te + seg * 32);
      const float4* cb = (const float4*)(cbias + seg * 32);
      #pragma unroll
      for (int i8 = 0; i8 < 4; i8++) {
        half8 hv;
        #pragma unroll
        for (int q = 0; q < 2; q++) {
          float4 e4 = ee[i8 * 2 + q], s4 = se[i8 * 2 + q], r4 = re[i8 * 2 + q];
          float4 t4 = te[i8 * 2 + q], c4 = cb[i8 * 2 + q];
          hv[q * 4 + 0] = (_Float16)fmaxf(e4.x + s4.x + tm * t4.x + r4.x + c4.x, 0.f);
          hv[q * 4 + 1] = (_Float16)fmaxf(e4.y + s4.y + tm * t4.y + r4.y + c4.y, 0.f);
          hv[q * 4 + 2] = (_Float16)fmaxf(e4.z + s4.z + tm * t4.z + r4.z + c4.z, 0.f);
          hv[q * 4 + 3] = (_Float16)fmaxf(e4.w + s4.w + tm * t4.w + r4.w + c4.w, 0.f);
        }
        int k0 = seg * 32 + i8 * 8;
        int byte = r * 512 + k0 * 2; byte ^= ((r & 7) << 4);
        *(half8*)(ab + byte) = hv;
      }
    } else {
      int k2b_ = (seg - 4) * 32;
      float at = att_seq[row], hi = hint_seq[row];
      const float4* wa = (const float4*)(W_b1 + k2b_);
      const float4* wh = (const float4*)(W_b1 + 128 + k2b_);
      const float4* bb = (const float4*)(b_b1 + k2b_);
      #pragma unroll
      for (int i8 = 0; i8 < 4; i8++) {
        half8 hv;
        #pragma unroll
        for (int q = 0; q < 2; q++) {
          float4 a4 = wa[i8 * 2 + q], h4 = wh[i8 * 2 + q], b4 = bb[i8 * 2 + q];
          hv[q * 4 + 0] = (_Float16)fmaxf(at * a4.x + hi * h4.x + b4.x, 0.f);
          hv[q * 4 + 1] = (_Float16)fmaxf(at * a4.y + hi * h4.y + b4.y, 0.f);
          hv[q * 4 + 2] = (_Float16)fmaxf(at * a4.z + hi * h4.z + b4.z, 0.f);
          hv[q * 4 + 3] = (_Float16)fmaxf(at * a4.w + hi * h4.w + b4.w, 0.f);
        }
        int k0 = 128 + k2b_ + i8 * 8;
        int byte = r * 512 + k0 * 2; byte ^= ((r & 7) << 4);
        *(half8*)(ab + byte) = hv;
      }
    }
  }
  __syncthreads();

  f32x4 acc[4][2] = {};
  const char* ab = (const char*)Ah;
  #pragma unroll
  for (int kt = 0; kt < 8; kt++) {
    #pragma unroll
    for (int mr = 0; mr < 4; mr++) {
      int byte = (mr * 16 + c) * 512 + kt * 64 + g * 16; byte ^= ((c & 7) << 4);
      half8 a = *(const half8*)(ab + byte);
      acc[mr][0] = __builtin_amdgcn_mfma_f32_16x16x32_f16(a, bfr[0][kt], acc[mr][0], 0, 0, 0);
      acc[mr][1] = __builtin_amdgcn_mfma_f32_16x16x32_f16(a, bfr[1][kt], acc[mr][1], 0, 0, 0);
    }
  }

  bool isL = (w < 4);
  float addc[2], wiv[2];
  int coff[2];
  #pragma unroll
  for (int ncl = 0; ncl < 2; ncl++) {
    int j = w * 32 + ncl * 16 + c;
    if (isL) { addc[ncl] = c_lg[j]; wiv[ncl] = NEGLAM * Wiv[j]; coff[ncl] = j * 4; }
    else     { addc[ncl] = c_fg[j - 128]; wiv[ncl] = 0.f; coff[ncl] = (j - 128) * 4 + 1; }
  }
  #pragma unroll
  for (int mr = 0; mr < 4; mr++) {
    #pragma unroll
    for (int rr = 0; rr < 4; rr++) {
      int rl = mr * 16 + g * 4 + rr;
      int row = rowbase + rl;
      float iv = ivs[rl];
      size_t base = (size_t)(row >> 9) * 131072 + (size_t)((row & 511) >> 1) * 512 + (row & 1) * 2;
      #pragma unroll
      for (int ncl = 0; ncl < 2; ncl++) {
        float v = acc[mr][ncl][rr] + addc[ncl] + iv * wiv[ncl];
        PRE[base + coff[ncl]] = (f16)v;
      }
    }
  }
}

// ---------------- K4: last-step nb fixup (PRE2, L slot of t=511) ----------------
__global__ __launch_bounds__(128) void k4_fix(
    const float* att_seq, const float* hint_seq,
    const float* W_b1, const float* b_b1,
    const float* M_lnb, const float* fix_l, f16* PRE) {
  int b = blockIdx.x, j = threadIdx.x;
  int row = b * SS + (SS - 1);
  __shared__ float rb_s[128];
  float v = att_seq[row] * W_b1[j] + hint_seq[row] * W_b1[128 + j] + b_b1[j];
  rb_s[j] = fmaxf(v, 0.f);
  __syncthreads();
  float a = fix_l[j];
  for (int m = 0; m < 128; m++) a += rb_s[m] * M_lnb[m * 128 + j];
  size_t idx = (size_t)b * 131072 + 255 * 512 + 2 + j * 4;
  PRE[idx] = (f16)((float)PRE[idx] - a);
}

// ---------------- K5: MFMA scan — 8 rows/block, 2 rows/thread uniform ---------
// 32 blocks x 512 thr. Block owns batch rows b*8..b*8+7, mapped to C-fragment
// rows {4g, 4g+1}; fragment rows 4g+2,4g+3 stay zero (init-once). Per-step:
// 1 PRE bank load, half the scalar work of the 16-row variant; 2 blocks/CU
// co-reside (independent barriers) for latency fill.
#define BAR() asm volatile("s_waitcnt lgkmcnt(0)\n\ts_barrier" ::: "memory")
#define MF(A, B, C) __builtin_amdgcn_mfma_f32_16x16x32_f16(A, B, C, 0, 0, 0)

__global__ __launch_bounds__(512, 2) void k5_scan_mfma(
    const f16* __restrict__ PRE, const f16* __restrict__ Wfrag,
    f16* __restrict__ h_blk) {
  __shared__ _Float16 AhA[2048], AhB[2048], Alg[2048];
  int tid = threadIdx.x;
  int w = tid >> 6, lane = tid & 63;
  int c = lane & 15, g = lane >> 4;
  int b = blockIdx.x;

  // zero all three buffers (dead fragment rows must stay zero forever)
  if (tid < 256) {
    ((float4*)AhA)[tid] = make_float4(0.f, 0.f, 0.f, 0.f);
    ((float4*)AhB)[tid] = make_float4(0.f, 0.f, 0.f, 0.f);
    ((float4*)Alg)[tid] = make_float4(0.f, 0.f, 0.f, 0.f);
  }

  half8 bL[4], bFH[4], bFL[4];
  const half8* wp = (const half8*)Wfrag;
  #pragma unroll
  for (int t4 = 0; t4 < 4; t4++) {
    bL [t4] = wp[((0 * 8 + w) * 4 + t4) * 64 + lane];
    bFH[t4] = wp[((1 * 8 + w) * 4 + t4) * 64 + lane];
    bFL[t4] = wp[((2 * 8 + w) * 4 + t4) * 64 + lane];
  }

  int rd[4], wr[2];
  #pragma unroll
  for (int t4 = 0; t4 < 4; t4++) {
    int K8 = 4 * t4 + g;
    rd[t4] = K8 * 256 + (c ^ (K8 & 3)) * 16;
  }
  {
    int F = 16 * w + c;
    int K8w = F >> 3, q = K8w & 3;
    #pragma unroll
    for (int r = 0; r < 2; r++)
      wr[r] = K8w * 256 + ((4 * g + r) ^ q) * 16 + (F & 7) * 2;
  }

  int col = 16 * w + c;
  const f16* pr[2]; f16* hb4[2];
  float hstate[2] = {0.f, 0.f};
  float lgf[2];
  half4_ pA[4][2], pB[4][2];   // [pair][row] banks
  half4_ hb[2];
  #pragma unroll
  for (int r = 0; r < 2; r++) {
    int br = b * 8 + g * 2 + r;
    pr[r]  = PRE + (size_t)br * 131072 + col * 4;
    hb4[r] = h_blk + (size_t)br * 65536 + col * 4;
  }
  // prologue: pairs 0..3 into bank A (pair stride 1024 B)
  #pragma unroll
  for (int p = 0; p < 4; p++)
    #pragma unroll
    for (int r = 0; r < 2; r++)
      pA[p][r] = *(const half4_*)((const char*)pr[r] + p * 1024);
  __syncthreads();

  const f32x4 Z4 = {0.f, 0.f, 0.f, 0.f};

#define STEPX(SRC, DST, CB, P, PAR, LB, LOFF, I0, TIN, FLUSH, DOINC)             \
  {                                                                              \
    half8 ha[4];                                                                 \
    _Pragma("unroll")                                                            \
    for (int t4 = 0; t4 < 4; t4++)                                               \
      ha[t4] = *(const half8*)((const char*)(SRC) + rd[t4]);                     \
    if (DOINC) {                                                                 \
      _Pragma("unroll")                                                          \
      for (int r = 0; r < 2; r++) pr[r] += 4096;                                 \
    }                                                                            \
    { const int p_ = (I0) >> 1, r_ = (I0) & 1;                                   \
      LB[p_][r_] = *(const half4_*)((const char*)pr[r_] + (LOFF) + p_ * 1024); } \
    f32x4 cL = Z4, cF = Z4;                                                      \
    _Pragma("unroll")                                                            \
    for (int r = 0; r < 2; r++) {                                                \
      cL[r] = (float)CB[P][r][(PAR) * 2];                                        \
      cF[r] = (float)CB[P][r][(PAR) * 2 + 1];                                    \
    }                                                                            \
    __builtin_amdgcn_s_setprio(1);                                               \
    f32x4 aLa = cL, aLb = Z4;                                                    \
    aLa = MF(ha[0], bL[0], aLa);                                                 \
    aLb = MF(ha[2], bL[2], aLb);                                                 \
    aLa = MF(ha[1], bL[1], aLa);                                                 \
    aLb = MF(ha[3], bL[3], aLb);                                                 \
    __builtin_amdgcn_s_setprio(0);                                               \
    _Pragma("unroll")                                                            \
    for (int r = 0; r < 2; r++) {                                                \
      lgf[r] = sigm_pre(aLa[r] + aLb[r]);                                        \
      *(_Float16*)((char*)Alg + wr[r]) = (_Float16)lgf[r];                       \
    }                                                                            \
    BAR();                                                                       \
    half8 la[4];                                                                 \
    _Pragma("unroll")                                                            \
    for (int t4 = 0; t4 < 4; t4++)                                               \
      la[t4] = *(const half8*)((const char*)Alg + rd[t4]);                       \
    __builtin_amdgcn_s_setprio(1);                                               \
    f32x4 aHa = cF, aHb = Z4;                                                    \
    aHa = MF(ha[0], bFH[0], aHa);                                                \
    aHb = MF(ha[2], bFH[2], aHb);                                                \
    aHa = MF(ha[1], bFH[1], aHa);                                                \
    aHb = MF(ha[3], bFH[3], aHb);                                                \
    aHa = MF(la[0], bFL[0], aHa);                                                \
    aHb = MF(la[2], bFL[2], aHb);                                                \
    aHa = MF(la[1], bFL[1], aHa);                                                \
    aHb = MF(la[3], bFL[3], aHb);                                                \
    __builtin_amdgcn_s_setprio(0);                                               \
    _Pragma("unroll")                                                            \
    for (int r = 0; r < 2; r++) {                                                \
      float fg = sigm_pre(aHa[r] + aHb[r]);                                      \
      float hn = lgf[r] + fg * hstate[r];                                        \
      hstate[r] = hn;                                                            \
      _Float16 hv = (_Float16)hn;                                                \
      *(_Float16*)((char*)(DST) + wr[r]) = hv;                                   \
      hb[r][TIN] = hv;                                                           \
    }                                                                            \
    if ((FLUSH) >= 0) {                                                          \
      _Pragma("unroll")                                                          \
      for (int r = 0; r < 2; r++)                                                \
        *(half4_*)((char*)hb4[r] + (FLUSH)) = hb[r];                             \
    }                                                                            \
    BAR();                                                                       \
  }

  for (int it = 0; it < 32; ++it) {
    STEPX(AhA, AhB, pA, 0, 0, pB, 4096, 0, 0,   -1, 0);
    STEPX(AhB, AhA, pA, 0, 1, pB, 4096, 1, 1,   -1, 0);
    STEPX(AhA, AhB, pA, 1, 0, pB, 4096, 2, 2,   -1, 0);
    STEPX(AhB, AhA, pA, 1, 1, pB, 4096, 3, 3,    0, 0);
    STEPX(AhA, AhB, pA, 2, 0, pB, 4096, 4, 0,   -1, 0);
    STEPX(AhB, AhA, pA, 2, 1, pB, 4096, 5, 1,   -1, 0);
    STEPX(AhA, AhB, pA, 3, 0, pB, 4096, 6, 2,   -1, 0);
    STEPX(AhB, AhA, pA, 3, 1, pB, 4096, 7, 3, 1024, 0);
    STEPX(AhA, AhB, pB, 0, 0, pA, 0,    0, 0,   -1, 1);
    STEPX(AhB, AhA, pB, 0, 1, pA, 0,    1, 1,   -1, 0);
    STEPX(AhA, AhB, pB, 1, 0, pA, 0,    2, 2,   -1, 0);
    STEPX(AhB, AhA, pB, 1, 1, pA, 0,    3, 3, 2048, 0);
    STEPX(AhA, AhB, pB, 2, 0, pA, 0,    4, 0,   -1, 0);
    STEPX(AhB, AhA, pB, 2, 1, pA, 0,    5, 1,   -1, 0);
    STEPX(AhA, AhB, pB, 3, 0, pA, 0,    6, 2,   -1, 0);
    STEPX(AhB, AhA, pB, 3, 1, pA, 0,    7, 3, 3072, 0);
    #pragma unroll
    for (int r = 0; r < 2; r++) hb4[r] += 2048;
  }
#undef STEPX
}

// ---------------- K6: prediction dot-products (blocked h layout) ----------------
__global__ __launch_bounds__(256) void k6_pred(
    const f16* h_blk, const int* ex_seq, const float* pe,
    const float* W_pred, const float* b_pred, float* out) {
  int tid = threadIdx.x;
  int wv = tid >> 6, lane = tid & 63;
  int task = blockIdx.x * 4 + wv;        // 0..32767
  int br = task >> 7, t4b = task & 127;
  const f16* hp = h_blk + ((size_t)br * 128 + t4b) * 128 * 4;
  half4_ h0 = *(const half4_*)(hp + lane * 4);
  half4_ h1 = *(const half4_*)(hp + (lane + 64) * 4);
  float w0 = W_pred[lane], w1 = W_pred[lane + 64];
  float s[4];
  #pragma unroll
  for (int q = 0; q < 4; q++) s[q] = (float)h0[q] * w0 + (float)h1[q] * w1;
  #pragma unroll
  for (int m = 1; m < 64; m <<= 1) {
    #pragma unroll
    for (int q = 0; q < 4; q++) s[q] += __shfl_xor(s[q], m);
  }
  if (lane == 0) {
    int4 ex = *(const int4*)(ex_seq + (size_t)br * 512 + t4b * 4);
    float bb = b_pred[0];
    float4 o;
    o.x = sigm(s[0] + pe[ex.x] + bb);
    o.y = sigm(s[1] + pe[ex.y] + bb);
    o.z = sigm(s[2] + pe[ex.z] + bb);
    o.w = sigm(s[3] + pe[ex.w] + bb);
    *(float4*)(out + (size_t)br * 512 + t4b * 4) = o;
  }
}

extern "C" void kernel_launch(void* const* d_in, const int* in_sizes, int n_in,
                              void* d_out, int out_size, void* d_ws, size_t ws_size,
                              hipStream_t stream) {
  const int*   ex_seq   = (const int*)d_in[0];
  const int*   sk_seq   = (const int*)d_in[1];
  const int*   re_seq   = (const int*)d_in[2];
  const float* time_seq = (const float*)d_in[3];
  const float* interval_seq = (const float*)d_in[4];
  const float* att_seq  = (const float*)d_in[5];
  const float* hint_seq = (const float*)d_in[6];
  // d_in[7] q_matrix: unused
  const float* ex_emb   = (const float*)d_in[8];
  const float* sk_emb   = (const float*)d_in[9];
  const float* re_emb   = (const float*)d_in[10];
  const float* W_time   = (const float*)d_in[11];
  const float* b_time   = (const float*)d_in[12];
  const float* W_int    = (const float*)d_in[13];
  const float* b_int    = (const float*)d_in[14];
  const float* W_b1     = (const float*)d_in[15];
  const float* b_b1     = (const float*)d_in[16];
  const float* W_b2     = (const float*)d_in[17];
  const float* b_b2     = (const float*)d_in[18];
  const float* W_learn  = (const float*)d_in[19];
  const float* b_learn  = (const float*)d_in[20];
  const float* W_forget = (const float*)d_in[21];
  const float* b_forget = (const float*)d_in[22];
  const float* W_pred   = (const float*)d_in[23];
  const float* b_pred   = (const float*)d_in[24];

  char* ws = (char*)d_ws;
  float* Ee    = (float*)(ws);              // 10,240,000
  float* Se    = (float*)(ws + 10240000);
  float* Re    = (float*)(ws + 10496000);
  float* Te    = (float*)(ws + 10497024);
  float* cbias = (float*)(ws + 10497536);
  float* c_lg  = (float*)(ws + 10498048);
  float* c_fg  = (float*)(ws + 10498560);
  float* fix_l = (float*)(ws + 10499072);
  float* M_lnb = (float*)(ws + 10761728);   // 65,536
  f16*   PRE   = (f16*)  (ws + 10827264);   // 67,108,864  (pair-interleaved PRE2)
  f16*   h_blk = (f16*)  (ws + 77936128);   // 33,554,432 (blocked layout)
  f16*   Wfrag = (f16*)  (ws + 111490560);  // 98,304
  float* pe    = (float*)(ws + 111588864);  // 80,000 -> total 111,668,864
  // aliased scratch:
  f16*   Bfrag = (f16*)  (ws + 77936128);   // aliases h_blk head (dead until k5)

  k012_prep<<<dim3(4734), dim3(256), 0, stream>>>(
      ex_emb, sk_emb, re_emb, W_time, b_time, W_int, b_int, W_b2, b_b2,
      W_learn, b_learn, W_forget, b_forget, W_pred,
      Ee, Se, Re, Te, cbias, c_lg, c_fg, fix_l, M_lnb, Wfrag, pe, Bfrag);
  k3_gemm_mfma<<<dim3(2048), dim3(512), 0, stream>>>(
      ex_seq, sk_seq, re_seq, time_seq, interval_seq, att_seq, hint_seq,
      W_b1, b_b1, W_learn + 256 * 128, Ee, Se, Re, Te, cbias, c_lg, c_fg, Bfrag, PRE);
  k4_fix<<<dim3(256), dim3(128), 0, stream>>>(
      att_seq, hint_seq, W_b1, b_b1, M_lnb, fix_l, PRE);
  k5_scan_mfma<<<dim3(32), dim3(512), 0, stream>>>(PRE, Wfrag, h_blk);
  k6_pred<<<dim3(8192), dim3(256), 0, stream>>>(
      h_blk, ex_seq, pe, W_pred, b_pred, (float*)d_out);
}

// Round 14
// 300.307 us; speedup vs baseline: 9.2808x; 1.0934x over previous
//
#include <hip/hip_runtime.h>
#include <hip/hip_fp16.h>

#define BB 256
#define SS 512
#define EE_N 20000
#define NEGLAM -1.442695041f
typedef _Float16 f16;
typedef __attribute__((ext_vector_type(8))) _Float16 half8;
typedef __attribute__((ext_vector_type(4))) _Float16 half4_;
typedef __attribute__((ext_vector_type(2))) _Float16 half2_;
typedef __attribute__((ext_vector_type(4))) float f32x4;

__device__ __forceinline__ float sigm(float x) {
  return __builtin_amdgcn_rcpf(1.0f + __builtin_amdgcn_exp2f(NEGLAM * x));
}
__device__ __forceinline__ float sigm_pre(float s) {
  return __builtin_amdgcn_rcpf(1.0f + __builtin_amdgcn_exp2f(s));
}

// ---------------- K012: fused prep (folds + Ee + wprep + pe + Bfrag) ---------
__global__ __launch_bounds__(256) void k012_prep(
    const float* ex_emb, const float* skill_emb, const float* response_emb,
    const float* W_time, const float* b_time,
    const float* W_int, const float* b_int,
    const float* W_b2, const float* b_b2,
    const float* W_learn, const float* b_learn,
    const float* W_forget, const float* b_forget,
    const float* W_pred,
    float* Ee, float* Se, float* Re, float* Te, float* cbias,
    float* c_lg, float* c_fg, float* fix_l,
    float* M_lnb, f16* Wfrag, float* pe, f16* Bfrag) {
  __shared__ float es[8 * 128];
  int blk = blockIdx.x, tid = threadIdx.x;
  if (blk < 2500) {
    *(float4*)&es[tid * 4] = *(const float4*)&ex_emb[(size_t)blk * 1024 + tid * 4];
    __syncthreads();
    int d = tid & 127, rg = tid >> 7;
    float a0 = 0, a1 = 0, a2 = 0, a3 = 0;
    for (int k = 0; k < 128; k++) {
      float w = W_int[k * 128 + d];
      a0 += es[(rg * 4 + 0) * 128 + k] * w;
      a1 += es[(rg * 4 + 1) * 128 + k] * w;
      a2 += es[(rg * 4 + 2) * 128 + k] * w;
      a3 += es[(rg * 4 + 3) * 128 + k] * w;
    }
    Ee[((size_t)blk * 8 + rg * 4 + 0) * 128 + d] = a0;
    Ee[((size_t)blk * 8 + rg * 4 + 1) * 128 + d] = a1;
    Ee[((size_t)blk * 8 + rg * 4 + 2) * 128 + d] = a2;
    Ee[((size_t)blk * 8 + rg * 4 + 3) * 128 + d] = a3;
  } else if (blk < 3388) {
    int b0 = blk - 2500, j = tid;
    if (j < 128) {
      if (b0 < 500) {
        float a = 0.f;
        for (int k = 0; k < 128; k++) a += skill_emb[b0 * 128 + k] * W_int[(128 + k) * 128 + j];
        Se[b0 * 128 + j] = a;
      } else if (b0 < 502) {
        int i = b0 - 500; float a = 0.f;
        for (int k = 0; k < 128; k++) a += response_emb[i * 128 + k] * W_int[(384 + k) * 128 + j];
        Re[i * 128 + j] = a;
      } else if (b0 == 502) {
        float a = 0.f, c = 0.f;
        for (int k = 0; k < 128; k++) {
          float w = W_int[(256 + k) * 128 + j];
          a += W_time[k] * w; c += b_time[k] * w;
        }
        Te[j] = a; cbias[j] = b_int[j] + c;
      } else if (b0 < 503 + 128) {
        int k = b0 - 503;
        int kt = k >> 5, gg = (k >> 3) & 3, e = k & 7;
        int nct = j >> 4, cc = j & 15;
        float vL = NEGLAM * W_learn[(128 + k) * 128 + j];
        float vF = NEGLAM * W_forget[(128 + k) * 128 + j];
        Bfrag[((size_t)((nct * 8 + kt) * 64) + gg * 16 + cc) * 8 + e] = (f16)vL;
        Bfrag[((size_t)(((8 + nct) * 8 + kt) * 64) + gg * 16 + cc) * 8 + e] = (f16)vF;
      } else if (b0 < 631 + 128) {
        int k2 = b0 - 631; float a = 0.f, c = 0.f;
        for (int m = 0; m < 128; m++) {
          float w = W_b2[k2 * 128 + m];
          a += w * (W_learn[(257 + m) * 128 + j] + W_learn[(385 + m) * 128 + j]);
          c += w * W_forget[(384 + m) * 128 + j];
        }
        int krow = 128 + k2;
        int kt = krow >> 5, gg = (krow >> 3) & 3, e = krow & 7;
        int nct = j >> 4, cc = j & 15;
        Bfrag[((size_t)((nct * 8 + kt) * 64) + gg * 16 + cc) * 8 + e] = (f16)(NEGLAM * a);
        Bfrag[((size_t)(((8 + nct) * 8 + kt) * 64) + gg * 16 + cc) * 8 + e] = (f16)(NEGLAM * c);
      } else if (b0 < 759 + 128) {
        int k = b0 - 759; float a = 0.f;
        for (int m = 0; m < 128; m++) a += W_b2[k * 128 + m] * W_learn[(385 + m) * 128 + j];
        M_lnb[k * 128 + j] = NEGLAM * a;
      } else {
        float a = 0.f, c = 0.f, f = 0.f;
        for (int m = 0; m < 128; m++) {
          float w = b_b2[m];
          a += w * (W_learn[(257 + m) * 128 + j] + W_learn[(385 + m) * 128 + j]);
          c += w * W_forget[(384 + m) * 128 + j];
          f += w * W_learn[(385 + m) * 128 + j];
        }
        c_lg[j] = NEGLAM * (b_learn[j] + a);
        c_fg[j] = NEGLAM * (b_forget[j] + c);
        fix_l[j] = NEGLAM * f;
      }
    }
  } else if (blk < 3484) {
    int b2 = blk - 3388;                // 0..95 = (mat*8 + w)*4 + t4
    if (tid < 64) {
      int mat = b2 >> 5, rem = b2 & 31, w = rem >> 2, t4 = rem & 3;
      int lane = tid, cc = lane & 15, gg = lane >> 4;
      const float* src = (mat == 0) ? W_learn : (mat == 1 ? W_forget : W_forget + 256 * 128);
      f16* dst = Wfrag + ((size_t)b2 * 64 + lane) * 8;
      #pragma unroll
      for (int e = 0; e < 8; e++) {
        int k = t4 * 32 + gg * 8 + e;
        int j = 16 * w + cc;
        dst[e] = (f16)(NEGLAM * src[k * 128 + j]);
      }
    }
  } else {
    int b3 = blk - 3484;
    int w = tid >> 6, l = tid & 63, g = l >> 4, li = l & 15;
    int row = b3 * 16 + w * 4 + g;
    const float4* ep = (const float4*)(ex_emb + (size_t)row * 128 + li * 8);
    const float4* wp = (const float4*)(W_pred + 128 + li * 8);
    float4 e0 = ep[0], e1 = ep[1], w0 = wp[0], w1 = wp[1];
    float s = e0.x * w0.x + e0.y * w0.y + e0.z * w0.z + e0.w * w0.w
            + e1.x * w1.x + e1.y * w1.y + e1.z * w1.z + e1.w * w1.w;
    #pragma unroll
    for (int m = 1; m < 16; m <<= 1) s += __shfl_xor(s, m);
    if (li == 0) pe[row] = s;
  }
}

// ---------------- K3: fused pre-activation GEMM via MFMA ----------------
// PRE2 layout: [br][t>>1][col][t&1][{L,F}] f16 — 512 elem (1024 B) per t-pair.
__global__ __launch_bounds__(512) void k3_gemm_mfma(
    const int* ex_seq, const int* sk_seq, const int* re_seq,
    const float* time_seq, const float* interval_seq,
    const float* att_seq, const float* hint_seq,
    const float* W_b1, const float* b_b1,
    const float* Wiv,
    const float* Ee, const float* Se, const float* Re,
    const float* Te, const float* cbias,
    const float* c_lg, const float* c_fg,
    const f16* Bfrag, f16* PRE) {
  __shared__ _Float16 Ah[64 * 256];
  __shared__ float ivs[64];
  int tid = threadIdx.x;
  int w = tid >> 6, lane = tid & 63;
  int c = lane & 15, g = lane >> 4;
  int rowbase = blockIdx.x * 64;

  half8 bfr[2][8];
  const half8* bp = (const half8*)Bfrag;
  #pragma unroll
  for (int ncl = 0; ncl < 2; ncl++)
    #pragma unroll
    for (int kt = 0; kt < 8; kt++)
      bfr[ncl][kt] = bp[((size_t)((w * 2 + ncl) * 8 + kt)) * 64 + lane];

  {
    int r = tid & 63, seg = tid >> 6;
    int row = rowbase + r;
    if (seg == 0) ivs[r] = interval_seq[row];
    char* ab = (char*)Ah;
    if (seg < 4) {
      int ex = ex_seq[row], sk = sk_seq[row], rp = re_seq[row];
      float tm = time_seq[row];
      const float4* ee = (const float4*)(Ee + (size_t)ex * 128 + seg * 32);
      const float4* se = (const float4*)(Se + (size_t)sk * 128 + seg * 32);
      const float4* re = (const float4*)(Re + (size_t)rp * 128 + seg * 32);
      const float4* te = (const float4*)(Te + seg * 32);
      const float4* cb = (const float4*)(cbias + seg * 32);
      #pragma unroll
      for (int i8 = 0; i8 < 4; i8++) {
        half8 hv;
        #pragma unroll
        for (int q = 0; q < 2; q++) {
          float4 e4 = ee[i8 * 2 + q], s4 = se[i8 * 2 + q], r4 = re[i8 * 2 + q];
          float4 t4 = te[i8 * 2 + q], c4 = cb[i8 * 2 + q];
          hv[q * 4 + 0] = (_Float16)fmaxf(e4.x + s4.x + tm * t4.x + r4.x + c4.x, 0.f);
          hv[q * 4 + 1] = (_Float16)fmaxf(e4.y + s4.y + tm * t4.y + r4.y + c4.y, 0.f);
          hv[q * 4 + 2] = (_Float16)fmaxf(e4.z + s4.z + tm * t4.z + r4.z + c4.z, 0.f);
          hv[q * 4 + 3] = (_Float16)fmaxf(e4.w + s4.w + tm * t4.w + r4.w + c4.w, 0.f);
        }
        int k0 = seg * 32 + i8 * 8;
        int byte = r * 512 + k0 * 2; byte ^= ((r & 7) << 4);
        *(half8*)(ab + byte) = hv;
      }
    } else {
      int k2b_ = (seg - 4) * 32;
      float at = att_seq[row], hi = hint_seq[row];
      const float4* wa = (const float4*)(W_b1 + k2b_);
      const float4* wh = (const float4*)(W_b1 + 128 + k2b_);
      const float4* bb = (const float4*)(b_b1 + k2b_);
      #pragma unroll
      for (int i8 = 0; i8 < 4; i8++) {
        half8 hv;
        #pragma unroll
        for (int q = 0; q < 2; q++) {
          float4 a4 = wa[i8 * 2 + q], h4 = wh[i8 * 2 + q], b4 = bb[i8 * 2 + q];
          hv[q * 4 + 0] = (_Float16)fmaxf(at * a4.x + hi * h4.x + b4.x, 0.f);
          hv[q * 4 + 1] = (_Float16)fmaxf(at * a4.y + hi * h4.y + b4.y, 0.f);
          hv[q * 4 + 2] = (_Float16)fmaxf(at * a4.z + hi * h4.z + b4.z, 0.f);
          hv[q * 4 + 3] = (_Float16)fmaxf(at * a4.w + hi * h4.w + b4.w, 0.f);
        }
        int k0 = 128 + k2b_ + i8 * 8;
        int byte = r * 512 + k0 * 2; byte ^= ((r & 7) << 4);
        *(half8*)(ab + byte) = hv;
      }
    }
  }
  __syncthreads();

  f32x4 acc[4][2] = {};
  const char* ab = (const char*)Ah;
  #pragma unroll
  for (int kt = 0; kt < 8; kt++) {
    #pragma unroll
    for (int mr = 0; mr < 4; mr++) {
      int byte = (mr * 16 + c) * 512 + kt * 64 + g * 16; byte ^= ((c & 7) << 4);
      half8 a = *(const half8*)(ab + byte);
      acc[mr][0] = __builtin_amdgcn_mfma_f32_16x16x32_f16(a, bfr[0][kt], acc[mr][0], 0, 0, 0);
      acc[mr][1] = __builtin_amdgcn_mfma_f32_16x16x32_f16(a, bfr[1][kt], acc[mr][1], 0, 0, 0);
    }
  }

  bool isL = (w < 4);
  float addc[2], wiv[2];
  int coff[2];
  #pragma unroll
  for (int ncl = 0; ncl < 2; ncl++) {
    int j = w * 32 + ncl * 16 + c;
    if (isL) { addc[ncl] = c_lg[j]; wiv[ncl] = NEGLAM * Wiv[j]; coff[ncl] = j * 4; }
    else     { addc[ncl] = c_fg[j - 128]; wiv[ncl] = 0.f; coff[ncl] = (j - 128) * 4 + 1; }
  }
  #pragma unroll
  for (int mr = 0; mr < 4; mr++) {
    #pragma unroll
    for (int rr = 0; rr < 4; rr++) {
      int rl = mr * 16 + g * 4 + rr;
      int row = rowbase + rl;
      float iv = ivs[rl];
      size_t base = (size_t)(row >> 9) * 131072 + (size_t)((row & 511) >> 1) * 512 + (row & 1) * 2;
      #pragma unroll
      for (int ncl = 0; ncl < 2; ncl++) {
        float v = acc[mr][ncl][rr] + addc[ncl] + iv * wiv[ncl];
        PRE[base + coff[ncl]] = (f16)v;
      }
    }
  }
}

// ---------------- K4: last-step nb fixup (PRE2, L slot of t=511) ----------------
__global__ __launch_bounds__(128) void k4_fix(
    const float* att_seq, const float* hint_seq,
    const float* W_b1, const float* b_b1,
    const float* M_lnb, const float* fix_l, f16* PRE) {
  int b = blockIdx.x, j = threadIdx.x;
  int row = b * SS + (SS - 1);
  __shared__ float rb_s[128];
  float v = att_seq[row] * W_b1[j] + hint_seq[row] * W_b1[128 + j] + b_b1[j];
  rb_s[j] = fmaxf(v, 0.f);
  __syncthreads();
  float a = fix_l[j];
  for (int m = 0; m < 128; m++) a += rb_s[m] * M_lnb[m * 128 + j];
  size_t idx = (size_t)b * 131072 + 255 * 512 + 2 + j * 4;
  PRE[idx] = (f16)((float)PRE[idx] - a);
}

// ---------------- K5: MFMA scan — 4 rows/block, 1 row/thread uniform ----------
// 64 blocks x 512 thr. Block owns batch rows b*4..b*4+3, mapped to C-fragment
// rows {4g}; other fragment rows stay zero (init-once). Per-step: 0.5 PRE bank
// loads, 1 sigmoid pair, 1 ds_write per phase — half of r13's scalar work.
#define BAR() asm volatile("s_waitcnt lgkmcnt(0)\n\ts_barrier" ::: "memory")
#define MF(A, B, C) __builtin_amdgcn_mfma_f32_16x16x32_f16(A, B, C, 0, 0, 0)

__global__ __launch_bounds__(512, 2) void k5_scan_mfma(
    const f16* __restrict__ PRE, const f16* __restrict__ Wfrag,
    f16* __restrict__ h_blk) {
  __shared__ _Float16 AhA[2048], AhB[2048], Alg[2048];
  int tid = threadIdx.x;
  int w = tid >> 6, lane = tid & 63;
  int c = lane & 15, g = lane >> 4;
  int b = blockIdx.x;

  // zero all three buffers (dead fragment rows must stay zero forever)
  if (tid < 256) {
    ((float4*)AhA)[tid] = make_float4(0.f, 0.f, 0.f, 0.f);
    ((float4*)AhB)[tid] = make_float4(0.f, 0.f, 0.f, 0.f);
    ((float4*)Alg)[tid] = make_float4(0.f, 0.f, 0.f, 0.f);
  }

  half8 bL[4], bFH[4], bFL[4];
  const half8* wp = (const half8*)Wfrag;
  #pragma unroll
  for (int t4 = 0; t4 < 4; t4++) {
    bL [t4] = wp[((0 * 8 + w) * 4 + t4) * 64 + lane];
    bFH[t4] = wp[((1 * 8 + w) * 4 + t4) * 64 + lane];
    bFL[t4] = wp[((2 * 8 + w) * 4 + t4) * 64 + lane];
  }

  int rd[4], wr0;
  #pragma unroll
  for (int t4 = 0; t4 < 4; t4++) {
    int K8 = 4 * t4 + g;
    rd[t4] = K8 * 256 + (c ^ (K8 & 3)) * 16;
  }
  {
    int F = 16 * w + c;
    int K8w = F >> 3, q = K8w & 3;
    wr0 = K8w * 256 + ((4 * g) ^ q) * 16 + (F & 7) * 2;
  }

  int col = 16 * w + c;
  int br = b * 4 + g;
  const f16* pr0 = PRE + (size_t)br * 131072 + col * 4;
  f16* hb40 = h_blk + (size_t)br * 65536 + col * 4;
  float hstate = 0.f;
  float lgf0;
  half4_ pA[4], pB[4];   // [pair] banks, single row
  half4_ hb0;
  // prologue: pairs 0..3 into bank A (pair stride 1024 B)
  #pragma unroll
  for (int p = 0; p < 4; p++)
    pA[p] = *(const half4_*)((const char*)pr0 + p * 1024);
  __syncthreads();

  const f32x4 Z4 = {0.f, 0.f, 0.f, 0.f};

#define STEPX(SRC, DST, CB, P, PAR, LB, LOFF, I0, TIN, FLUSH, DOINC)             \
  {                                                                              \
    half8 ha[4];                                                                 \
    _Pragma("unroll")                                                            \
    for (int t4 = 0; t4 < 4; t4++)                                               \
      ha[t4] = *(const half8*)((const char*)(SRC) + rd[t4]);                     \
    if (DOINC) pr0 += 4096;                                                      \
    if ((I0) >= 0)                                                               \
      LB[(I0)] = *(const half4_*)((const char*)pr0 + (LOFF) + (I0) * 1024);      \
    f32x4 cL = Z4, cF = Z4;                                                      \
    cL[0] = (float)CB[P][(PAR) * 2];                                             \
    cF[0] = (float)CB[P][(PAR) * 2 + 1];                                         \
    __builtin_amdgcn_s_setprio(1);                                               \
    f32x4 aLa = cL, aLb = Z4;                                                    \
    aLa = MF(ha[0], bL[0], aLa);                                                 \
    aLb = MF(ha[2], bL[2], aLb);                                                 \
    aLa = MF(ha[1], bL[1], aLa);                                                 \
    aLb = MF(ha[3], bL[3], aLb);                                                 \
    __builtin_amdgcn_s_setprio(0);                                               \
    lgf0 = sigm_pre(aLa[0] + aLb[0]);                                            \
    *(_Float16*)((char*)Alg + wr0) = (_Float16)lgf0;                             \
    BAR();                                                                       \
    half8 la[4];                                                                 \
    _Pragma("unroll")                                                            \
    for (int t4 = 0; t4 < 4; t4++)                                               \
      la[t4] = *(const half8*)((const char*)Alg + rd[t4]);                       \
    __builtin_amdgcn_s_setprio(1);                                               \
    f32x4 aHa = cF, aHb = Z4;                                                    \
    aHa = MF(ha[0], bFH[0], aHa);                                                \
    aHb = MF(ha[2], bFH[2], aHb);                                                \
    aHa = MF(ha[1], bFH[1], aHa);                                                \
    aHb = MF(ha[3], bFH[3], aHb);                                                \
    aHa = MF(la[0], bFL[0], aHa);                                                \
    aHb = MF(la[2], bFL[2], aHb);                                                \
    aHa = MF(la[1], bFL[1], aHa);                                                \
    aHb = MF(la[3], bFL[3], aHb);                                                \
    __builtin_amdgcn_s_setprio(0);                                               \
    {                                                                            \
      float fg = sigm_pre(aHa[0] + aHb[0]);                                      \
      float hn = lgf0 + fg * hstate;                                             \
      hstate = hn;                                                               \
      _Float16 hv = (_Float16)hn;                                                \
      *(_Float16*)((char*)(DST) + wr0) = hv;                                     \
      hb0[TIN] = hv;                                                             \
    }                                                                            \
    if ((FLUSH) >= 0)                                                            \
      *(half4_*)((char*)hb40 + (FLUSH)) = hb0;                                   \
    BAR();                                                                       \
  }

  for (int it = 0; it < 32; ++it) {
    STEPX(AhA, AhB, pA, 0, 0, pB, 4096,  0, 0,   -1, 0);
    STEPX(AhB, AhA, pA, 0, 1, pB, 4096, -1, 1,   -1, 0);
    STEPX(AhA, AhB, pA, 1, 0, pB, 4096,  1, 2,   -1, 0);
    STEPX(AhB, AhA, pA, 1, 1, pB, 4096, -1, 3,    0, 0);
    STEPX(AhA, AhB, pA, 2, 0, pB, 4096,  2, 0,   -1, 0);
    STEPX(AhB, AhA, pA, 2, 1, pB, 4096, -1, 1,   -1, 0);
    STEPX(AhA, AhB, pA, 3, 0, pB, 4096,  3, 2,   -1, 0);
    STEPX(AhB, AhA, pA, 3, 1, pB, 4096, -1, 3, 1024, 0);
    STEPX(AhA, AhB, pB, 0, 0, pA, 0,     0, 0,   -1, 1);
    STEPX(AhB, AhA, pB, 0, 1, pA, 0,    -1, 1,   -1, 0);
    STEPX(AhA, AhB, pB, 1, 0, pA, 0,     1, 2,   -1, 0);
    STEPX(AhB, AhA, pB, 1, 1, pA, 0,    -1, 3, 2048, 0);
    STEPX(AhA, AhB, pB, 2, 0, pA, 0,     2, 0,   -1, 0);
    STEPX(AhB, AhA, pB, 2, 1, pA, 0,    -1, 1,   -1, 0);
    STEPX(AhA, AhB, pB, 3, 0, pA, 0,     3, 2,   -1, 0);
    STEPX(AhB, AhA, pB, 3, 1, pA, 0,    -1, 3, 3072, 0);
    hb40 += 2048;
  }
#undef STEPX
}

// ---------------- K6: prediction dot-products (blocked h layout) ----------------
__global__ __launch_bounds__(256) void k6_pred(
    const f16* h_blk, const int* ex_seq, const float* pe,
    const float* W_pred, const float* b_pred, float* out) {
  int tid = threadIdx.x;
  int wv = tid >> 6, lane = tid & 63;
  int task = blockIdx.x * 4 + wv;        // 0..32767
  int br = task >> 7, t4b = task & 127;
  const f16* hp = h_blk + ((size_t)br * 128 + t4b) * 128 * 4;
  half4_ h0 = *(const half4_*)(hp + lane * 4);
  half4_ h1 = *(const half4_*)(hp + (lane + 64) * 4);
  float w0 = W_pred[lane], w1 = W_pred[lane + 64];
  float s[4];
  #pragma unroll
  for (int q = 0; q < 4; q++) s[q] = (float)h0[q] * w0 + (float)h1[q] * w1;
  #pragma unroll
  for (int m = 1; m < 64; m <<= 1) {
    #pragma unroll
    for (int q = 0; q < 4; q++) s[q] += __shfl_xor(s[q], m);
  }
  if (lane == 0) {
    int4 ex = *(const int4*)(ex_seq + (size_t)br * 512 + t4b * 4);
    float bb = b_pred[0];
    float4 o;
    o.x = sigm(s[0] + pe[ex.x] + bb);
    o.y = sigm(s[1] + pe[ex.y] + bb);
    o.z = sigm(s[2] + pe[ex.z] + bb);
    o.w = sigm(s[3] + pe[ex.w] + bb);
    *(float4*)(out + (size_t)br * 512 + t4b * 4) = o;
  }
}

extern "C" void kernel_launch(void* const* d_in, const int* in_sizes, int n_in,
                              void* d_out, int out_size, void* d_ws, size_t ws_size,
                              hipStream_t stream) {
  const int*   ex_seq   = (const int*)d_in[0];
  const int*   sk_seq   = (const int*)d_in[1];
  const int*   re_seq   = (const int*)d_in[2];
  const float* time_seq = (const float*)d_in[3];
  const float* interval_seq = (const float*)d_in[4];
  const float* att_seq  = (const float*)d_in[5];
  const float* hint_seq = (const float*)d_in[6];
  // d_in[7] q_matrix: unused
  const float* ex_emb   = (const float*)d_in[8];
  const float* sk_emb   = (const float*)d_in[9];
  const float* re_emb   = (const float*)d_in[10];
  const float* W_time   = (const float*)d_in[11];
  const float* b_time   = (const float*)d_in[12];
  const float* W_int    = (const float*)d_in[13];
  const float* b_int    = (const float*)d_in[14];
  const float* W_b1     = (const float*)d_in[15];
  const float* b_b1     = (const float*)d_in[16];
  const float* W_b2     = (const float*)d_in[17];
  const float* b_b2     = (const float*)d_in[18];
  const float* W_learn  = (const float*)d_in[19];
  const float* b_learn  = (const float*)d_in[20];
  const float* W_forget = (const float*)d_in[21];
  const float* b_forget = (const float*)d_in[22];
  const float* W_pred   = (const float*)d_in[23];
  const float* b_pred   = (const float*)d_in[24];

  char* ws = (char*)d_ws;
  float* Ee    = (float*)(ws);              // 10,240,000
  float* Se    = (float*)(ws + 10240000);
  float* Re    = (float*)(ws + 10496000);
  float* Te    = (float*)(ws + 10497024);
  float* cbias = (float*)(ws + 10497536);
  float* c_lg  = (float*)(ws + 10498048);
  float* c_fg  = (float*)(ws + 10498560);
  float* fix_l = (float*)(ws + 10499072);
  float* M_lnb = (float*)(ws + 10761728);   // 65,536
  f16*   PRE   = (f16*)  (ws + 10827264);   // 67,108,864  (pair-interleaved PRE2)
  f16*   h_blk = (f16*)  (ws + 77936128);   // 33,554,432 (blocked layout)
  f16*   Wfrag = (f16*)  (ws + 111490560);  // 98,304
  float* pe    = (float*)(ws + 111588864);  // 80,000 -> total 111,668,864
  // aliased scratch:
  f16*   Bfrag = (f16*)  (ws + 77936128);   // aliases h_blk head (dead until k5)

  k012_prep<<<dim3(4734), dim3(256), 0, stream>>>(
      ex_emb, sk_emb, re_emb, W_time, b_time, W_int, b_int, W_b2, b_b2,
      W_learn, b_learn, W_forget, b_forget, W_pred,
      Ee, Se, Re, Te, cbias, c_lg, c_fg, fix_l, M_lnb, Wfrag, pe, Bfrag);
  k3_gemm_mfma<<<dim3(2048), dim3(512), 0, stream>>>(
      ex_seq, sk_seq, re_seq, time_seq, interval_seq, att_seq, hint_seq,
      W_b1, b_b1, W_learn + 256 * 128, Ee, Se, Re, Te, cbias, c_lg, c_fg, Bfrag, PRE);
  k4_fix<<<dim3(256), dim3(128), 0, stream>>>(
      att_seq, hint_seq, W_b1, b_b1, M_lnb, fix_l, PRE);
  k5_scan_mfma<<<dim3(64), dim3(512), 0, stream>>>(PRE, Wfrag, h_blk);
  k6_pred<<<dim3(8192), dim3(256), 0, stream>>>(
      h_blk, ex_seq, pe, W_pred, b_pred, (float*)d_out);
}

// Round 15
// 292.146 us; speedup vs baseline: 9.5400x; 1.0279x over previous
//
#include <hip/hip_runtime.h>
#include <hip/hip_fp16.h>

#define BB 256
#define SS 512
#define EE_N 20000
#define NEGLAM -1.442695041f
typedef _Float16 f16;
typedef __attribute__((ext_vector_type(8))) _Float16 half8;
typedef __attribute__((ext_vector_type(4))) _Float16 half4_;
typedef __attribute__((ext_vector_type(2))) _Float16 half2_;
typedef __attribute__((ext_vector_type(4))) float f32x4;

__device__ __forceinline__ float sigm(float x) {
  return __builtin_amdgcn_rcpf(1.0f + __builtin_amdgcn_exp2f(NEGLAM * x));
}
__device__ __forceinline__ float sigm_pre(float s) {
  return __builtin_amdgcn_rcpf(1.0f + __builtin_amdgcn_exp2f(s));
}

// ---------------- K012: fused prep (folds + Ee + wprep + pe + Bfrag) ---------
__global__ __launch_bounds__(256) void k012_prep(
    const float* ex_emb, const float* skill_emb, const float* response_emb,
    const float* W_time, const float* b_time,
    const float* W_int, const float* b_int,
    const float* W_b2, const float* b_b2,
    const float* W_learn, const float* b_learn,
    const float* W_forget, const float* b_forget,
    const float* W_pred,
    float* Ee, float* Se, float* Re, float* Te, float* cbias,
    float* c_lg, float* c_fg, float* fix_l,
    float* M_lnb, f16* Wfrag, float* pe, f16* Bfrag) {
  __shared__ float es[8 * 128];
  int blk = blockIdx.x, tid = threadIdx.x;
  if (blk < 2500) {
    *(float4*)&es[tid * 4] = *(const float4*)&ex_emb[(size_t)blk * 1024 + tid * 4];
    __syncthreads();
    int d = tid & 127, rg = tid >> 7;
    float a0 = 0, a1 = 0, a2 = 0, a3 = 0;
    for (int k = 0; k < 128; k++) {
      float w = W_int[k * 128 + d];
      a0 += es[(rg * 4 + 0) * 128 + k] * w;
      a1 += es[(rg * 4 + 1) * 128 + k] * w;
      a2 += es[(rg * 4 + 2) * 128 + k] * w;
      a3 += es[(rg * 4 + 3) * 128 + k] * w;
    }
    Ee[((size_t)blk * 8 + rg * 4 + 0) * 128 + d] = a0;
    Ee[((size_t)blk * 8 + rg * 4 + 1) * 128 + d] = a1;
    Ee[((size_t)blk * 8 + rg * 4 + 2) * 128 + d] = a2;
    Ee[((size_t)blk * 8 + rg * 4 + 3) * 128 + d] = a3;
  } else if (blk < 3388) {
    int b0 = blk - 2500, j = tid;
    if (j < 128) {
      if (b0 < 500) {
        float a = 0.f;
        for (int k = 0; k < 128; k++) a += skill_emb[b0 * 128 + k] * W_int[(128 + k) * 128 + j];
        Se[b0 * 128 + j] = a;
      } else if (b0 < 502) {
        int i = b0 - 500; float a = 0.f;
        for (int k = 0; k < 128; k++) a += response_emb[i * 128 + k] * W_int[(384 + k) * 128 + j];
        Re[i * 128 + j] = a;
      } else if (b0 == 502) {
        float a = 0.f, c = 0.f;
        for (int k = 0; k < 128; k++) {
          float w = W_int[(256 + k) * 128 + j];
          a += W_time[k] * w; c += b_time[k] * w;
        }
        Te[j] = a; cbias[j] = b_int[j] + c;
      } else if (b0 < 503 + 128) {
        int k = b0 - 503;
        int kt = k >> 5, gg = (k >> 3) & 3, e = k & 7;
        int nct = j >> 4, cc = j & 15;
        float vL = NEGLAM * W_learn[(128 + k) * 128 + j];
        float vF = NEGLAM * W_forget[(128 + k) * 128 + j];
        Bfrag[((size_t)((nct * 8 + kt) * 64) + gg * 16 + cc) * 8 + e] = (f16)vL;
        Bfrag[((size_t)(((8 + nct) * 8 + kt) * 64) + gg * 16 + cc) * 8 + e] = (f16)vF;
      } else if (b0 < 631 + 128) {
        int k2 = b0 - 631; float a = 0.f, c = 0.f;
        for (int m = 0; m < 128; m++) {
          float w = W_b2[k2 * 128 + m];
          a += w * (W_learn[(257 + m) * 128 + j] + W_learn[(385 + m) * 128 + j]);
          c += w * W_forget[(384 + m) * 128 + j];
        }
        int krow = 128 + k2;
        int kt = krow >> 5, gg = (krow >> 3) & 3, e = krow & 7;
        int nct = j >> 4, cc = j & 15;
        Bfrag[((size_t)((nct * 8 + kt) * 64) + gg * 16 + cc) * 8 + e] = (f16)(NEGLAM * a);
        Bfrag[((size_t)(((8 + nct) * 8 + kt) * 64) + gg * 16 + cc) * 8 + e] = (f16)(NEGLAM * c);
      } else if (b0 < 759 + 128) {
        int k = b0 - 759; float a = 0.f;
        for (int m = 0; m < 128; m++) a += W_b2[k * 128 + m] * W_learn[(385 + m) * 128 + j];
        M_lnb[k * 128 + j] = NEGLAM * a;
      } else {
        float a = 0.f, c = 0.f, f = 0.f;
        for (int m = 0; m < 128; m++) {
          float w = b_b2[m];
          a += w * (W_learn[(257 + m) * 128 + j] + W_learn[(385 + m) * 128 + j]);
          c += w * W_forget[(384 + m) * 128 + j];
          f += w * W_learn[(385 + m) * 128 + j];
        }
        c_lg[j] = NEGLAM * (b_learn[j] + a);
        c_fg[j] = NEGLAM * (b_forget[j] + c);
        fix_l[j] = NEGLAM * f;
      }
    }
  } else if (blk < 3484) {
    int b2 = blk - 3388;                // 0..95 = (mat*8 + w)*4 + t4
    if (tid < 64) {
      int mat = b2 >> 5, rem = b2 & 31, w = rem >> 2, t4 = rem & 3;
      int lane = tid, cc = lane & 15, gg = lane >> 4;
      const float* src = (mat == 0) ? W_learn : (mat == 1 ? W_forget : W_forget + 256 * 128);
      f16* dst = Wfrag + ((size_t)b2 * 64 + lane) * 8;
      #pragma unroll
      for (int e = 0; e < 8; e++) {
        int k = t4 * 32 + gg * 8 + e;
        int j = 16 * w + cc;
        dst[e] = (f16)(NEGLAM * src[k * 128 + j]);
      }
    }
  } else {
    int b3 = blk - 3484;
    int w = tid >> 6, l = tid & 63, g = l >> 4, li = l & 15;
    int row = b3 * 16 + w * 4 + g;
    const float4* ep = (const float4*)(ex_emb + (size_t)row * 128 + li * 8);
    const float4* wp = (const float4*)(W_pred + 128 + li * 8);
    float4 e0 = ep[0], e1 = ep[1], w0 = wp[0], w1 = wp[1];
    float s = e0.x * w0.x + e0.y * w0.y + e0.z * w0.z + e0.w * w0.w
            + e1.x * w1.x + e1.y * w1.y + e1.z * w1.z + e1.w * w1.w;
    #pragma unroll
    for (int m = 1; m < 16; m <<= 1) s += __shfl_xor(s, m);
    if (li == 0) pe[row] = s;
  }
}

// ---------------- K3: fused pre-activation GEMM via MFMA ----------------
// PRE2 layout: [br][t>>1][col][t&1][{L,F}] f16 — 512 elem (1024 B) per t-pair.
// Epilogue routes through LDS (Ah reuse) -> coalesced 32KB contiguous store.
__global__ __launch_bounds__(512) void k3_gemm_mfma(
    const int* ex_seq, const int* sk_seq, const int* re_seq,
    const float* time_seq, const float* interval_seq,
    const float* att_seq, const float* hint_seq,
    const float* W_b1, const float* b_b1,
    const float* Wiv,
    const float* Ee, const float* Se, const float* Re,
    const float* Te, const float* cbias,
    const float* c_lg, const float* c_fg,
    const f16* Bfrag, f16* PRE) {
  __shared__ _Float16 Ah[64 * 256];
  __shared__ float ivs[64];
  int tid = threadIdx.x;
  int w = tid >> 6, lane = tid & 63;
  int c = lane & 15, g = lane >> 4;
  int rowbase = blockIdx.x * 64;

  half8 bfr[2][8];
  const half8* bp = (const half8*)Bfrag;
  #pragma unroll
  for (int ncl = 0; ncl < 2; ncl++)
    #pragma unroll
    for (int kt = 0; kt < 8; kt++)
      bfr[ncl][kt] = bp[((size_t)((w * 2 + ncl) * 8 + kt)) * 64 + lane];

  {
    int r = tid & 63, seg = tid >> 6;
    int row = rowbase + r;
    if (seg == 0) ivs[r] = interval_seq[row];
    char* ab = (char*)Ah;
    if (seg < 4) {
      int ex = ex_seq[row], sk = sk_seq[row], rp = re_seq[row];
      float tm = time_seq[row];
      const float4* ee = (const float4*)(Ee + (size_t)ex * 128 + seg * 32);
      const float4* se = (const float4*)(Se + (size_t)sk * 128 + seg * 32);
      const float4* re = (const float4*)(Re + (size_t)rp * 128 + seg * 32);
      const float4* te = (const float4*)(Te + seg * 32);
      const float4* cb = (const float4*)(cbias + seg * 32);
      #pragma unroll
      for (int i8 = 0; i8 < 4; i8++) {
        half8 hv;
        #pragma unroll
        for (int q = 0; q < 2; q++) {
          float4 e4 = ee[i8 * 2 + q], s4 = se[i8 * 2 + q], r4 = re[i8 * 2 + q];
          float4 t4 = te[i8 * 2 + q], c4 = cb[i8 * 2 + q];
          hv[q * 4 + 0] = (_Float16)fmaxf(e4.x + s4.x + tm * t4.x + r4.x + c4.x, 0.f);
          hv[q * 4 + 1] = (_Float16)fmaxf(e4.y + s4.y + tm * t4.y + r4.y + c4.y, 0.f);
          hv[q * 4 + 2] = (_Float16)fmaxf(e4.z + s4.z + tm * t4.z + r4.z + c4.z, 0.f);
          hv[q * 4 + 3] = (_Float16)fmaxf(e4.w + s4.w + tm * t4.w + r4.w + c4.w, 0.f);
        }
        int k0 = seg * 32 + i8 * 8;
        int byte = r * 512 + k0 * 2; byte ^= ((r & 7) << 4);
        *(half8*)(ab + byte) = hv;
      }
    } else {
      int k2b_ = (seg - 4) * 32;
      float at = att_seq[row], hi = hint_seq[row];
      const float4* wa = (const float4*)(W_b1 + k2b_);
      const float4* wh = (const float4*)(W_b1 + 128 + k2b_);
      const float4* bb = (const float4*)(b_b1 + k2b_);
      #pragma unroll
      for (int i8 = 0; i8 < 4; i8++) {
        half8 hv;
        #pragma unroll
        for (int q = 0; q < 2; q++) {
          float4 a4 = wa[i8 * 2 + q], h4 = wh[i8 * 2 + q], b4 = bb[i8 * 2 + q];
          hv[q * 4 + 0] = (_Float16)fmaxf(at * a4.x + hi * h4.x + b4.x, 0.f);
          hv[q * 4 + 1] = (_Float16)fmaxf(at * a4.y + hi * h4.y + b4.y, 0.f);
          hv[q * 4 + 2] = (_Float16)fmaxf(at * a4.z + hi * h4.z + b4.z, 0.f);
          hv[q * 4 + 3] = (_Float16)fmaxf(at * a4.w + hi * h4.w + b4.w, 0.f);
        }
        int k0 = 128 + k2b_ + i8 * 8;
        int byte = r * 512 + k0 * 2; byte ^= ((r & 7) << 4);
        *(half8*)(ab + byte) = hv;
      }
    }
  }
  __syncthreads();

  f32x4 acc[4][2] = {};
  {
    const char* ab = (const char*)Ah;
    #pragma unroll
    for (int kt = 0; kt < 8; kt++) {
      #pragma unroll
      for (int mr = 0; mr < 4; mr++) {
        int byte = (mr * 16 + c) * 512 + kt * 64 + g * 16; byte ^= ((c & 7) << 4);
        half8 a = *(const half8*)(ab + byte);
        acc[mr][0] = __builtin_amdgcn_mfma_f32_16x16x32_f16(a, bfr[0][kt], acc[mr][0], 0, 0, 0);
        acc[mr][1] = __builtin_amdgcn_mfma_f32_16x16x32_f16(a, bfr[1][kt], acc[mr][1], 0, 0, 0);
      }
    }
  }
  __syncthreads();   // all Ah reads done -> safe to reuse Ah for epilogue

  bool isL = (w < 4);
  float addc[2], wiv[2];
  int colb[2];
  #pragma unroll
  for (int ncl = 0; ncl < 2; ncl++) {
    int j = w * 32 + ncl * 16 + c;
    if (isL) { addc[ncl] = c_lg[j]; wiv[ncl] = NEGLAM * Wiv[j]; colb[ncl] = j; }
    else     { addc[ncl] = c_fg[j - 128]; wiv[ncl] = 0.f; colb[ncl] = j - 128; }
  }
  int slot = isL ? 0 : 1;
  #pragma unroll
  for (int mr = 0; mr < 4; mr++) {
    #pragma unroll
    for (int rr = 0; rr < 4; rr++) {
      int rl = mr * 16 + g * 4 + rr;
      float iv = ivs[rl];
      #pragma unroll
      for (int ncl = 0; ncl < 2; ncl++) {
        float v = acc[mr][ncl][rr] + addc[ncl] + iv * wiv[ncl];
        int idx = (rl >> 1) * 512 + colb[ncl] * 4 + (rl & 1) * 2 + slot;
        Ah[idx] = (_Float16)v;
      }
    }
  }
  __syncthreads();
  // coalesced copy: 32KB contiguous PRE2 chunk for rows rowbase..rowbase+63
  {
    size_t outbase = (size_t)(rowbase >> 9) * 131072 + (size_t)((rowbase & 511) >> 1) * 512;
    const float4* src = (const float4*)Ah;
    float4* dst = (float4*)(PRE + outbase);
    #pragma unroll
    for (int p = 0; p < 4; p++)
      dst[p * 512 + tid] = src[p * 512 + tid];
  }
}

// ---------------- K4: last-step nb fixup (PRE2, L slot of t=511) ----------------
__global__ __launch_bounds__(128) void k4_fix(
    const float* att_seq, const float* hint_seq,
    const float* W_b1, const float* b_b1,
    const float* M_lnb, const float* fix_l, f16* PRE) {
  int b = blockIdx.x, j = threadIdx.x;
  int row = b * SS + (SS - 1);
  __shared__ float rb_s[128];
  float v = att_seq[row] * W_b1[j] + hint_seq[row] * W_b1[128 + j] + b_b1[j];
  rb_s[j] = fmaxf(v, 0.f);
  __syncthreads();
  float a = fix_l[j];
  for (int m = 0; m < 128; m++) a += rb_s[m] * M_lnb[m * 128 + j];
  size_t idx = (size_t)b * 131072 + 255 * 512 + 2 + j * 4;
  PRE[idx] = (f16)((float)PRE[idx] - a);
}

// ---------------- K5: MFMA scan — 4 rows/block, 1 row/thread uniform ----------
#define BAR() asm volatile("s_waitcnt lgkmcnt(0)\n\ts_barrier" ::: "memory")
#define MF(A, B, C) __builtin_amdgcn_mfma_f32_16x16x32_f16(A, B, C, 0, 0, 0)

__global__ __launch_bounds__(512, 2) void k5_scan_mfma(
    const f16* __restrict__ PRE, const f16* __restrict__ Wfrag,
    f16* __restrict__ h_blk) {
  __shared__ _Float16 AhA[2048], AhB[2048], Alg[2048];
  int tid = threadIdx.x;
  int w = tid >> 6, lane = tid & 63;
  int c = lane & 15, g = lane >> 4;
  int b = blockIdx.x;

  // zero all three buffers (dead fragment rows must stay zero forever)
  if (tid < 256) {
    ((float4*)AhA)[tid] = make_float4(0.f, 0.f, 0.f, 0.f);
    ((float4*)AhB)[tid] = make_float4(0.f, 0.f, 0.f, 0.f);
    ((float4*)Alg)[tid] = make_float4(0.f, 0.f, 0.f, 0.f);
  }

  half8 bL[4], bFH[4], bFL[4];
  const half8* wp = (const half8*)Wfrag;
  #pragma unroll
  for (int t4 = 0; t4 < 4; t4++) {
    bL [t4] = wp[((0 * 8 + w) * 4 + t4) * 64 + lane];
    bFH[t4] = wp[((1 * 8 + w) * 4 + t4) * 64 + lane];
    bFL[t4] = wp[((2 * 8 + w) * 4 + t4) * 64 + lane];
  }

  int rd[4], wr0;
  #pragma unroll
  for (int t4 = 0; t4 < 4; t4++) {
    int K8 = 4 * t4 + g;
    rd[t4] = K8 * 256 + (c ^ (K8 & 3)) * 16;
  }
  {
    int F = 16 * w + c;
    int K8w = F >> 3, q = K8w & 3;
    wr0 = K8w * 256 + ((4 * g) ^ q) * 16 + (F & 7) * 2;
  }

  int col = 16 * w + c;
  int br = b * 4 + g;
  const f16* pr0 = PRE + (size_t)br * 131072 + col * 4;
  f16* hb40 = h_blk + (size_t)br * 65536 + col * 4;
  float hstate = 0.f;
  float lgf0;
  half4_ pA[4], pB[4];   // [pair] banks, single row
  half4_ hb0;
  // prologue: pairs 0..3 into bank A (pair stride 1024 B)
  #pragma unroll
  for (int p = 0; p < 4; p++)
    pA[p] = *(const half4_*)((const char*)pr0 + p * 1024);
  __syncthreads();

  const f32x4 Z4 = {0.f, 0.f, 0.f, 0.f};

#define STEPX(SRC, DST, CB, P, PAR, LB, LOFF, I0, TIN, FLUSH, DOINC)             \
  {                                                                              \
    half8 ha[4];                                                                 \
    _Pragma("unroll")                                                            \
    for (int t4 = 0; t4 < 4; t4++)                                               \
      ha[t4] = *(const half8*)((const char*)(SRC) + rd[t4]);                     \
    if (DOINC) pr0 += 4096;                                                      \
    if ((I0) >= 0)                                                               \
      LB[(I0)] = *(const half4_*)((const char*)pr0 + (LOFF) + (I0) * 1024);      \
    f32x4 cL = Z4, cF = Z4;                                                      \
    cL[0] = (float)CB[P][(PAR) * 2];                                             \
    cF[0] = (float)CB[P][(PAR) * 2 + 1];                                         \
    __builtin_amdgcn_s_setprio(1);                                               \
    f32x4 aLa = cL, aLb = Z4;                                                    \
    aLa = MF(ha[0], bL[0], aLa);                                                 \
    aLb = MF(ha[2], bL[2], aLb);                                                 \
    aLa = MF(ha[1], bL[1], aLa);                                                 \
    aLb = MF(ha[3], bL[3], aLb);                                                 \
    __builtin_amdgcn_s_setprio(0);                                               \
    lgf0 = sigm_pre(aLa[0] + aLb[0]);                                            \
    *(_Float16*)((char*)Alg + wr0) = (_Float16)lgf0;                             \
    BAR();                                                                       \
    half8 la[4];                                                                 \
    _Pragma("unroll")                                                            \
    for (int t4 = 0; t4 < 4; t4++)                                               \
      la[t4] = *(const half8*)((const char*)Alg + rd[t4]);                       \
    __builtin_amdgcn_s_setprio(1);                                               \
    f32x4 aHa = cF, aHb = Z4;                                                    \
    aHa = MF(ha[0], bFH[0], aHa);                                                \
    aHb = MF(ha[2], bFH[2], aHb);                                                \
    aHa = MF(ha[1], bFH[1], aHa);                                                \
    aHb = MF(ha[3], bFH[3], aHb);                                                \
    aHa = MF(la[0], bFL[0], aHa);                                                \
    aHb = MF(la[2], bFL[2], aHb);                                                \
    aHa = MF(la[1], bFL[1], aHa);                                                \
    aHb = MF(la[3], bFL[3], aHb);                                                \
    __builtin_amdgcn_s_setprio(0);                                               \
    {                                                                            \
      float fg = sigm_pre(aHa[0] + aHb[0]);                                      \
      float hn = lgf0 + fg * hstate;                                             \
      hstate = hn;                                                               \
      _Float16 hv = (_Float16)hn;                                                \
      *(_Float16*)((char*)(DST) + wr0) = hv;                                     \
      hb0[TIN] = hv;                                                             \
    }                                                                            \
    if ((FLUSH) >= 0)                                                            \
      *(half4_*)((char*)hb40 + (FLUSH)) = hb0;                                   \
    BAR();                                                                       \
  }

  for (int it = 0; it < 32; ++it) {
    STEPX(AhA, AhB, pA, 0, 0, pB, 4096,  0, 0,   -1, 0);
    STEPX(AhB, AhA, pA, 0, 1, pB, 4096, -1, 1,   -1, 0);
    STEPX(AhA, AhB, pA, 1, 0, pB, 4096,  1, 2,   -1, 0);
    STEPX(AhB, AhA, pA, 1, 1, pB, 4096, -1, 3,    0, 0);
    STEPX(AhA, AhB, pA, 2, 0, pB, 4096,  2, 0,   -1, 0);
    STEPX(AhB, AhA, pA, 2, 1, pB, 4096, -1, 1,   -1, 0);
    STEPX(AhA, AhB, pA, 3, 0, pB, 4096,  3, 2,   -1, 0);
    STEPX(AhB, AhA, pA, 3, 1, pB, 4096, -1, 3, 1024, 0);
    STEPX(AhA, AhB, pB, 0, 0, pA, 0,     0, 0,   -1, 1);
    STEPX(AhB, AhA, pB, 0, 1, pA, 0,    -1, 1,   -1, 0);
    STEPX(AhA, AhB, pB, 1, 0, pA, 0,     1, 2,   -1, 0);
    STEPX(AhB, AhA, pB, 1, 1, pA, 0,    -1, 3, 2048, 0);
    STEPX(AhA, AhB, pB, 2, 0, pA, 0,     2, 0,   -1, 0);
    STEPX(AhB, AhA, pB, 2, 1, pA, 0,    -1, 1,   -1, 0);
    STEPX(AhA, AhB, pB, 3, 0, pA, 0,     3, 2,   -1, 0);
    STEPX(AhB, AhA, pB, 3, 1, pA, 0,    -1, 3, 3072, 0);
    hb40 += 2048;
  }
#undef STEPX
}

// ---------------- K6: prediction dot-products (blocked h layout) ----------------
__global__ __launch_bounds__(256) void k6_pred(
    const f16* h_blk, const int* ex_seq, const float* pe,
    const float* W_pred, const float* b_pred, float* out) {
  int tid = threadIdx.x;
  int wv = tid >> 6, lane = tid & 63;
  int task = blockIdx.x * 4 + wv;        // 0..32767
  int br = task >> 7, t4b = task & 127;
  const f16* hp = h_blk + ((size_t)br * 128 + t4b) * 128 * 4;
  half4_ h0 = *(const half4_*)(hp + lane * 4);
  half4_ h1 = *(const half4_*)(hp + (lane + 64) * 4);
  float w0 = W_pred[lane], w1 = W_pred[lane + 64];
  float s[4];
  #pragma unroll
  for (int q = 0; q < 4; q++) s[q] = (float)h0[q] * w0 + (float)h1[q] * w1;
  #pragma unroll
  for (int m = 1; m < 64; m <<= 1) {
    #pragma unroll
    for (int q = 0; q < 4; q++) s[q] += __shfl_xor(s[q], m);
  }
  if (lane == 0) {
    int4 ex = *(const int4*)(ex_seq + (size_t)br * 512 + t4b * 4);
    float bb = b_pred[0];
    float4 o;
    o.x = sigm(s[0] + pe[ex.x] + bb);
    o.y = sigm(s[1] + pe[ex.y] + bb);
    o.z = sigm(s[2] + pe[ex.z] + bb);
    o.w = sigm(s[3] + pe[ex.w] + bb);
    *(float4*)(out + (size_t)br * 512 + t4b * 4) = o;
  }
}

extern "C" void kernel_launch(void* const* d_in, const int* in_sizes, int n_in,
                              void* d_out, int out_size, void* d_ws, size_t ws_size,
                              hipStream_t stream) {
  const int*   ex_seq   = (const int*)d_in[0];
  const int*   sk_seq   = (const int*)d_in[1];
  const int*   re_seq   = (const int*)d_in[2];
  const float* time_seq = (const float*)d_in[3];
  const float* interval_seq = (const float*)d_in[4];
  const float* att_seq  = (const float*)d_in[5];
  const float* hint_seq = (const float*)d_in[6];
  // d_in[7] q_matrix: unused
  const float* ex_emb   = (const float*)d_in[8];
  const float* sk_emb   = (const float*)d_in[9];
  const float* re_emb   = (const float*)d_in[10];
  const float* W_time   = (const float*)d_in[11];
  const float* b_time   = (const float*)d_in[12];
  const float* W_int    = (const float*)d_in[13];
  const float* b_int    = (const float*)d_in[14];
  const float* W_b1     = (const float*)d_in[15];
  const float* b_b1     = (const float*)d_in[16];
  const float* W_b2     = (const float*)d_in[17];
  const float* b_b2     = (const float*)d_in[18];
  const float* W_learn  = (const float*)d_in[19];
  const float* b_learn  = (const float*)d_in[20];
  const float* W_forget = (const float*)d_in[21];
  const float* b_forget = (const float*)d_in[22];
  const float* W_pred   = (const float*)d_in[23];
  const float* b_pred   = (const float*)d_in[24];

  char* ws = (char*)d_ws;
  float* Ee    = (float*)(ws);              // 10,240,000
  float* Se    = (float*)(ws + 10240000);
  float* Re    = (float*)(ws + 10496000);
  float* Te    = (float*)(ws + 10497024);
  float* cbias = (float*)(ws + 10497536);
  float* c_lg  = (float*)(ws + 10498048);
  float* c_fg  = (float*)(ws + 10498560);
  float* fix_l = (float*)(ws + 10499072);
  float* M_lnb = (float*)(ws + 10761728);   // 65,536
  f16*   PRE   = (f16*)  (ws + 10827264);   // 67,108,864  (pair-interleaved PRE2)
  f16*   h_blk = (f16*)  (ws + 77936128);   // 33,554,432 (blocked layout)
  f16*   Wfrag = (f16*)  (ws + 111490560);  // 98,304
  float* pe    = (float*)(ws + 111588864);  // 80,000 -> total 111,668,864
  // aliased scratch:
  f16*   Bfrag = (f16*)  (ws + 77936128);   // aliases h_blk head (dead until k5)

  k012_prep<<<dim3(4734), dim3(256), 0, stream>>>(
      ex_emb, sk_emb, re_emb, W_time, b_time, W_int, b_int, W_b2, b_b2,
      W_learn, b_learn, W_forget, b_forget, W_pred,
      Ee, Se, Re, Te, cbias, c_lg, c_fg, fix_l, M_lnb, Wfrag, pe, Bfrag);
  k3_gemm_mfma<<<dim3(2048), dim3(512), 0, stream>>>(
      ex_seq, sk_seq, re_seq, time_seq, interval_seq, att_seq, hint_seq,
      W_b1, b_b1, W_learn + 256 * 128, Ee, Se, Re, Te, cbias, c_lg, c_fg, Bfrag, PRE);
  k4_fix<<<dim3(256), dim3(128), 0, stream>>>(
      att_seq, hint_seq, W_b1, b_b1, M_lnb, fix_l, PRE);
  k5_scan_mfma<<<dim3(64), dim3(512), 0, stream>>>(PRE, Wfrag, h_blk);
  k6_pred<<<dim3(8192), dim3(256), 0, stream>>>(
      h_blk, ex_seq, pe, W_pred, b_pred, (float*)d_out);
}

// Round 16
// 289.845 us; speedup vs baseline: 9.6158x; 1.0079x over previous
//
#include <hip/hip_runtime.h>
#include <hip/hip_fp16.h>

#define BB 256
#define SS 512
#define EE_N 20000
#define NEGLAM -1.442695041f
typedef _Float16 f16;
typedef __attribute__((ext_vector_type(8))) _Float16 half8;
typedef __attribute__((ext_vector_type(4))) _Float16 half4_;
typedef __attribute__((ext_vector_type(2))) _Float16 half2_;
typedef __attribute__((ext_vector_type(4))) float f32x4;

__device__ __forceinline__ float sigm(float x) {
  return __builtin_amdgcn_rcpf(1.0f + __builtin_amdgcn_exp2f(NEGLAM * x));
}
__device__ __forceinline__ float sigm_pre(float s) {
  return __builtin_amdgcn_rcpf(1.0f + __builtin_amdgcn_exp2f(s));
}

// ---------------- K1e: Ee = exercise_emb @ W_int[0:128,:] via MFMA ------------
// 313 blocks x 512 thr; 64 rows/block; wave w owns cols 16w..16w+15.
__global__ __launch_bounds__(512) void k1e_Ee(
    const float* __restrict__ ex_emb, const float* __restrict__ W_int,
    float* __restrict__ Ee) {
  __shared__ _Float16 As[64 * 128];   // 16KB, [row][k] f16, xor-swizzled
  int tid = threadIdx.x;
  int w = tid >> 6, lane = tid & 63;
  int c = lane & 15, g = lane >> 4;
  int rowbase = blockIdx.x * 64;

  // B-fragments direct from W_int (L2-hot): bfr[kt][e] = W_int[(kt*32+g*8+e)*128 + 16w+c]
  half8 bfr[4];
  #pragma unroll
  for (int kt = 0; kt < 4; kt++) {
    #pragma unroll
    for (int e = 0; e < 8; e++)
      bfr[kt][e] = (_Float16)W_int[(kt * 32 + g * 8 + e) * 128 + 16 * w + c];
  }

  // stage A: thread (r = tid&63, seg = tid>>6) loads row r, k = seg*16..seg*16+15
  {
    int r = tid & 63, seg = tid >> 6;
    int row = rowbase + r; if (row > EE_N - 1) row = EE_N - 1;
    const float4* src = (const float4*)(ex_emb + (size_t)row * 128 + seg * 16);
    char* ab = (char*)As;
    #pragma unroll
    for (int h = 0; h < 2; h++) {
      float4 v0 = src[h * 2], v1 = src[h * 2 + 1];
      half8 hv;
      hv[0] = (_Float16)v0.x; hv[1] = (_Float16)v0.y;
      hv[2] = (_Float16)v0.z; hv[3] = (_Float16)v0.w;
      hv[4] = (_Float16)v1.x; hv[5] = (_Float16)v1.y;
      hv[6] = (_Float16)v1.z; hv[7] = (_Float16)v1.w;
      int byte = r * 256 + seg * 32 + h * 16; byte ^= ((r & 7) << 4);
      *(half8*)(ab + byte) = hv;
    }
  }
  __syncthreads();

  f32x4 acc[4] = {};
  const char* ab = (const char*)As;
  #pragma unroll
  for (int kt = 0; kt < 4; kt++) {
    #pragma unroll
    for (int mr = 0; mr < 4; mr++) {
      int byte = (mr * 16 + c) * 256 + kt * 64 + g * 16; byte ^= ((c & 7) << 4);
      half8 a = *(const half8*)(ab + byte);
      acc[mr] = __builtin_amdgcn_mfma_f32_16x16x32_f16(a, bfr[kt], acc[mr], 0, 0, 0);
    }
  }
  #pragma unroll
  for (int mr = 0; mr < 4; mr++) {
    #pragma unroll
    for (int rr = 0; rr < 4; rr++) {
      int row = rowbase + mr * 16 + 4 * g + rr;
      if (row < EE_N) Ee[(size_t)row * 128 + 16 * w + c] = acc[mr][rr];
    }
  }
}

// ---------------- K012: fused prep (folds + wprep + pe + Bfrag) ----------------
// blocks 0..887: folds; 888..983: Wfrag; 984..2233: pe.
__global__ __launch_bounds__(256) void k012_prep(
    const float* ex_emb, const float* skill_emb, const float* response_emb,
    const float* W_time, const float* b_time,
    const float* W_int, const float* b_int,
    const float* W_b2, const float* b_b2,
    const float* W_learn, const float* b_learn,
    const float* W_forget, const float* b_forget,
    const float* W_pred,
    float* Se, float* Re, float* Te, float* cbias,
    float* c_lg, float* c_fg, float* fix_l,
    float* M_lnb, f16* Wfrag, float* pe, f16* Bfrag) {
  int blk = blockIdx.x, tid = threadIdx.x;
  if (blk < 888) {
    int b0 = blk, j = tid;
    if (j < 128) {
      if (b0 < 500) {
        float a = 0.f;
        for (int k = 0; k < 128; k++) a += skill_emb[b0 * 128 + k] * W_int[(128 + k) * 128 + j];
        Se[b0 * 128 + j] = a;
      } else if (b0 < 502) {
        int i = b0 - 500; float a = 0.f;
        for (int k = 0; k < 128; k++) a += response_emb[i * 128 + k] * W_int[(384 + k) * 128 + j];
        Re[i * 128 + j] = a;
      } else if (b0 == 502) {
        float a = 0.f, c = 0.f;
        for (int k = 0; k < 128; k++) {
          float w = W_int[(256 + k) * 128 + j];
          a += W_time[k] * w; c += b_time[k] * w;
        }
        Te[j] = a; cbias[j] = b_int[j] + c;
      } else if (b0 < 503 + 128) {
        int k = b0 - 503;
        int kt = k >> 5, gg = (k >> 3) & 3, e = k & 7;
        int nct = j >> 4, cc = j & 15;
        float vL = NEGLAM * W_learn[(128 + k) * 128 + j];
        float vF = NEGLAM * W_forget[(128 + k) * 128 + j];
        Bfrag[((size_t)((nct * 8 + kt) * 64) + gg * 16 + cc) * 8 + e] = (f16)vL;
        Bfrag[((size_t)(((8 + nct) * 8 + kt) * 64) + gg * 16 + cc) * 8 + e] = (f16)vF;
      } else if (b0 < 631 + 128) {
        int k2 = b0 - 631; float a = 0.f, c = 0.f;
        for (int m = 0; m < 128; m++) {
          float w = W_b2[k2 * 128 + m];
          a += w * (W_learn[(257 + m) * 128 + j] + W_learn[(385 + m) * 128 + j]);
          c += w * W_forget[(384 + m) * 128 + j];
        }
        int krow = 128 + k2;
        int kt = krow >> 5, gg = (krow >> 3) & 3, e = krow & 7;
        int nct = j >> 4, cc = j & 15;
        Bfrag[((size_t)((nct * 8 + kt) * 64) + gg * 16 + cc) * 8 + e] = (f16)(NEGLAM * a);
        Bfrag[((size_t)(((8 + nct) * 8 + kt) * 64) + gg * 16 + cc) * 8 + e] = (f16)(NEGLAM * c);
      } else if (b0 < 759 + 128) {
        int k = b0 - 759; float a = 0.f;
        for (int m = 0; m < 128; m++) a += W_b2[k * 128 + m] * W_learn[(385 + m) * 128 + j];
        M_lnb[k * 128 + j] = NEGLAM * a;
      } else {
        float a = 0.f, c = 0.f, f = 0.f;
        for (int m = 0; m < 128; m++) {
          float w = b_b2[m];
          a += w * (W_learn[(257 + m) * 128 + j] + W_learn[(385 + m) * 128 + j]);
          c += w * W_forget[(384 + m) * 128 + j];
          f += w * W_learn[(385 + m) * 128 + j];
        }
        c_lg[j] = NEGLAM * (b_learn[j] + a);
        c_fg[j] = NEGLAM * (b_forget[j] + c);
        fix_l[j] = NEGLAM * f;
      }
    }
  } else if (blk < 984) {
    int b2 = blk - 888;                 // 0..95 = (mat*8 + w)*4 + t4
    if (tid < 64) {
      int mat = b2 >> 5, rem = b2 & 31, w = rem >> 2, t4 = rem & 3;
      int lane = tid, cc = lane & 15, gg = lane >> 4;
      const float* src = (mat == 0) ? W_learn : (mat == 1 ? W_forget : W_forget + 256 * 128);
      f16* dst = Wfrag + ((size_t)b2 * 64 + lane) * 8;
      #pragma unroll
      for (int e = 0; e < 8; e++) {
        int k = t4 * 32 + gg * 8 + e;
        int j = 16 * w + cc;
        dst[e] = (f16)(NEGLAM * src[k * 128 + j]);
      }
    }
  } else {
    int b3 = blk - 984;
    int w = tid >> 6, l = tid & 63, g = l >> 4, li = l & 15;
    int row = b3 * 16 + w * 4 + g;
    const float4* ep = (const float4*)(ex_emb + (size_t)row * 128 + li * 8);
    const float4* wp = (const float4*)(W_pred + 128 + li * 8);
    float4 e0 = ep[0], e1 = ep[1], w0 = wp[0], w1 = wp[1];
    float s = e0.x * w0.x + e0.y * w0.y + e0.z * w0.z + e0.w * w0.w
            + e1.x * w1.x + e1.y * w1.y + e1.z * w1.z + e1.w * w1.w;
    #pragma unroll
    for (int m = 1; m < 16; m <<= 1) s += __shfl_xor(s, m);
    if (li == 0) pe[row] = s;
  }
}

// ---------------- K3: fused pre-activation GEMM via MFMA ----------------
// PRE2 layout: [br][t>>1][col][t&1][{L,F}] f16 — 512 elem (1024 B) per t-pair.
// Epilogue routes through LDS (Ah reuse) -> coalesced 32KB contiguous store.
__global__ __launch_bounds__(512) void k3_gemm_mfma(
    const int* ex_seq, const int* sk_seq, const int* re_seq,
    const float* time_seq, const float* interval_seq,
    const float* att_seq, const float* hint_seq,
    const float* W_b1, const float* b_b1,
    const float* Wiv,
    const float* Ee, const float* Se, const float* Re,
    const float* Te, const float* cbias,
    const float* c_lg, const float* c_fg,
    const f16* Bfrag, f16* PRE) {
  __shared__ _Float16 Ah[64 * 256];
  __shared__ float ivs[64];
  int tid = threadIdx.x;
  int w = tid >> 6, lane = tid & 63;
  int c = lane & 15, g = lane >> 4;
  int rowbase = blockIdx.x * 64;

  half8 bfr[2][8];
  const half8* bp = (const half8*)Bfrag;
  #pragma unroll
  for (int ncl = 0; ncl < 2; ncl++)
    #pragma unroll
    for (int kt = 0; kt < 8; kt++)
      bfr[ncl][kt] = bp[((size_t)((w * 2 + ncl) * 8 + kt)) * 64 + lane];

  {
    int r = tid & 63, seg = tid >> 6;
    int row = rowbase + r;
    if (seg == 0) ivs[r] = interval_seq[row];
    char* ab = (char*)Ah;
    if (seg < 4) {
      int ex = ex_seq[row], sk = sk_seq[row], rp = re_seq[row];
      float tm = time_seq[row];
      const float4* ee = (const float4*)(Ee + (size_t)ex * 128 + seg * 32);
      const float4* se = (const float4*)(Se + (size_t)sk * 128 + seg * 32);
      const float4* re = (const float4*)(Re + (size_t)rp * 128 + seg * 32);
      const float4* te = (const float4*)(Te + seg * 32);
      const float4* cb = (const float4*)(cbias + seg * 32);
      #pragma unroll
      for (int i8 = 0; i8 < 4; i8++) {
        half8 hv;
        #pragma unroll
        for (int q = 0; q < 2; q++) {
          float4 e4 = ee[i8 * 2 + q], s4 = se[i8 * 2 + q], r4 = re[i8 * 2 + q];
          float4 t4 = te[i8 * 2 + q], c4 = cb[i8 * 2 + q];
          hv[q * 4 + 0] = (_Float16)fmaxf(e4.x + s4.x + tm * t4.x + r4.x + c4.x, 0.f);
          hv[q * 4 + 1] = (_Float16)fmaxf(e4.y + s4.y + tm * t4.y + r4.y + c4.y, 0.f);
          hv[q * 4 + 2] = (_Float16)fmaxf(e4.z + s4.z + tm * t4.z + r4.z + c4.z, 0.f);
          hv[q * 4 + 3] = (_Float16)fmaxf(e4.w + s4.w + tm * t4.w + r4.w + c4.w, 0.f);
        }
        int k0 = seg * 32 + i8 * 8;
        int byte = r * 512 + k0 * 2; byte ^= ((r & 7) << 4);
        *(half8*)(ab + byte) = hv;
      }
    } else {
      int k2b_ = (seg - 4) * 32;
      float at = att_seq[row], hi = hint_seq[row];
      const float4* wa = (const float4*)(W_b1 + k2b_);
      const float4* wh = (const float4*)(W_b1 + 128 + k2b_);
      const float4* bb = (const float4*)(b_b1 + k2b_);
      #pragma unroll
      for (int i8 = 0; i8 < 4; i8++) {
        half8 hv;
        #pragma unroll
        for (int q = 0; q < 2; q++) {
          float4 a4 = wa[i8 * 2 + q], h4 = wh[i8 * 2 + q], b4 = bb[i8 * 2 + q];
          hv[q * 4 + 0] = (_Float16)fmaxf(at * a4.x + hi * h4.x + b4.x, 0.f);
          hv[q * 4 + 1] = (_Float16)fmaxf(at * a4.y + hi * h4.y + b4.y, 0.f);
          hv[q * 4 + 2] = (_Float16)fmaxf(at * a4.z + hi * h4.z + b4.z, 0.f);
          hv[q * 4 + 3] = (_Float16)fmaxf(at * a4.w + hi * h4.w + b4.w, 0.f);
        }
        int k0 = 128 + k2b_ + i8 * 8;
        int byte = r * 512 + k0 * 2; byte ^= ((r & 7) << 4);
        *(half8*)(ab + byte) = hv;
      }
    }
  }
  __syncthreads();

  f32x4 acc[4][2] = {};
  {
    const char* ab = (const char*)Ah;
    #pragma unroll
    for (int kt = 0; kt < 8; kt++) {
      #pragma unroll
      for (int mr = 0; mr < 4; mr++) {
        int byte = (mr * 16 + c) * 512 + kt * 64 + g * 16; byte ^= ((c & 7) << 4);
        half8 a = *(const half8*)(ab + byte);
        acc[mr][0] = __builtin_amdgcn_mfma_f32_16x16x32_f16(a, bfr[0][kt], acc[mr][0], 0, 0, 0);
        acc[mr][1] = __builtin_amdgcn_mfma_f32_16x16x32_f16(a, bfr[1][kt], acc[mr][1], 0, 0, 0);
      }
    }
  }
  __syncthreads();   // all Ah reads done -> safe to reuse Ah for epilogue

  bool isL = (w < 4);
  float addc[2], wiv[2];
  int colb[2];
  #pragma unroll
  for (int ncl = 0; ncl < 2; ncl++) {
    int j = w * 32 + ncl * 16 + c;
    if (isL) { addc[ncl] = c_lg[j]; wiv[ncl] = NEGLAM * Wiv[j]; colb[ncl] = j; }
    else     { addc[ncl] = c_fg[j - 128]; wiv[ncl] = 0.f; colb[ncl] = j - 128; }
  }
  int slot = isL ? 0 : 1;
  #pragma unroll
  for (int mr = 0; mr < 4; mr++) {
    #pragma unroll
    for (int rr = 0; rr < 4; rr++) {
      int rl = mr * 16 + g * 4 + rr;
      float iv = ivs[rl];
      #pragma unroll
      for (int ncl = 0; ncl < 2; ncl++) {
        float v = acc[mr][ncl][rr] + addc[ncl] + iv * wiv[ncl];
        int idx = (rl >> 1) * 512 + colb[ncl] * 4 + (rl & 1) * 2 + slot;
        Ah[idx] = (_Float16)v;
      }
    }
  }
  __syncthreads();
  {
    size_t outbase = (size_t)(rowbase >> 9) * 131072 + (size_t)((rowbase & 511) >> 1) * 512;
    const float4* src = (const float4*)Ah;
    float4* dst = (float4*)(PRE + outbase);
    #pragma unroll
    for (int p = 0; p < 4; p++)
      dst[p * 512 + tid] = src[p * 512 + tid];
  }
}

// ---------------- K4: last-step nb fixup (PRE2, L slot of t=511) ----------------
__global__ __launch_bounds__(128) void k4_fix(
    const float* att_seq, const float* hint_seq,
    const float* W_b1, const float* b_b1,
    const float* M_lnb, const float* fix_l, f16* PRE) {
  int b = blockIdx.x, j = threadIdx.x;
  int row = b * SS + (SS - 1);
  __shared__ float rb_s[128];
  float v = att_seq[row] * W_b1[j] + hint_seq[row] * W_b1[128 + j] + b_b1[j];
  rb_s[j] = fmaxf(v, 0.f);
  __syncthreads();
  float a = fix_l[j];
  for (int m = 0; m < 128; m++) a += rb_s[m] * M_lnb[m * 128 + j];
  size_t idx = (size_t)b * 131072 + 255 * 512 + 2 + j * 4;
  PRE[idx] = (f16)((float)PRE[idx] - a);
}

// ---------------- K5: MFMA scan — 4 rows/block, 1 row/thread uniform ----------
#define BAR() asm volatile("s_waitcnt lgkmcnt(0)\n\ts_barrier" ::: "memory")
#define MF(A, B, C) __builtin_amdgcn_mfma_f32_16x16x32_f16(A, B, C, 0, 0, 0)

__global__ __launch_bounds__(512, 2) void k5_scan_mfma(
    const f16* __restrict__ PRE, const f16* __restrict__ Wfrag,
    f16* __restrict__ h_blk) {
  __shared__ _Float16 AhA[2048], AhB[2048], Alg[2048];
  int tid = threadIdx.x;
  int w = tid >> 6, lane = tid & 63;
  int c = lane & 15, g = lane >> 4;
  int b = blockIdx.x;

  if (tid < 256) {
    ((float4*)AhA)[tid] = make_float4(0.f, 0.f, 0.f, 0.f);
    ((float4*)AhB)[tid] = make_float4(0.f, 0.f, 0.f, 0.f);
    ((float4*)Alg)[tid] = make_float4(0.f, 0.f, 0.f, 0.f);
  }

  half8 bL[4], bFH[4], bFL[4];
  const half8* wp = (const half8*)Wfrag;
  #pragma unroll
  for (int t4 = 0; t4 < 4; t4++) {
    bL [t4] = wp[((0 * 8 + w) * 4 + t4) * 64 + lane];
    bFH[t4] = wp[((1 * 8 + w) * 4 + t4) * 64 + lane];
    bFL[t4] = wp[((2 * 8 + w) * 4 + t4) * 64 + lane];
  }

  int rd[4], wr0;
  #pragma unroll
  for (int t4 = 0; t4 < 4; t4++) {
    int K8 = 4 * t4 + g;
    rd[t4] = K8 * 256 + (c ^ (K8 & 3)) * 16;
  }
  {
    int F = 16 * w + c;
    int K8w = F >> 3, q = K8w & 3;
    wr0 = K8w * 256 + ((4 * g) ^ q) * 16 + (F & 7) * 2;
  }

  int col = 16 * w + c;
  int br = b * 4 + g;
  const f16* pr0 = PRE + (size_t)br * 131072 + col * 4;
  f16* hb40 = h_blk + (size_t)br * 65536 + col * 4;
  float hstate = 0.f;
  float lgf0;
  half4_ pA[4], pB[4];
  half4_ hb0;
  #pragma unroll
  for (int p = 0; p < 4; p++)
    pA[p] = *(const half4_*)((const char*)pr0 + p * 1024);
  __syncthreads();

  const f32x4 Z4 = {0.f, 0.f, 0.f, 0.f};

#define STEPX(SRC, DST, CB, P, PAR, LB, LOFF, I0, TIN, FLUSH, DOINC)             \
  {                                                                              \
    half8 ha[4];                                                                 \
    _Pragma("unroll")                                                            \
    for (int t4 = 0; t4 < 4; t4++)                                               \
      ha[t4] = *(const half8*)((const char*)(SRC) + rd[t4]);                     \
    if (DOINC) pr0 += 4096;                                                      \
    if ((I0) >= 0)                                                               \
      LB[(I0)] = *(const half4_*)((const char*)pr0 + (LOFF) + (I0) * 1024);      \
    f32x4 cL = Z4, cF = Z4;                                                      \
    cL[0] = (float)CB[P][(PAR) * 2];                                             \
    cF[0] = (float)CB[P][(PAR) * 2 + 1];                                         \
    __builtin_amdgcn_s_setprio(1);                                               \
    f32x4 aLa = cL, aLb = Z4;                                                    \
    aLa = MF(ha[0], bL[0], aLa);                                                 \
    aLb = MF(ha[2], bL[2], aLb);                                                 \
    aLa = MF(ha[1], bL[1], aLa);                                                 \
    aLb = MF(ha[3], bL[3], aLb);                                                 \
    __builtin_amdgcn_s_setprio(0);                                               \
    lgf0 = sigm_pre(aLa[0] + aLb[0]);                                            \
    *(_Float16*)((char*)Alg + wr0) = (_Float16)lgf0;                             \
    BAR();                                                                       \
    half8 la[4];                                                                 \
    _Pragma("unroll")                                                            \
    for (int t4 = 0; t4 < 4; t4++)                                               \
      la[t4] = *(const half8*)((const char*)Alg + rd[t4]);                       \
    __builtin_amdgcn_s_setprio(1);                                               \
    f32x4 aHa = cF, aHb = Z4;                                                    \
    aHa = MF(ha[0], bFH[0], aHa);                                                \
    aHb = MF(ha[2], bFH[2], aHb);                                                \
    aHa = MF(ha[1], bFH[1], aHa);                                                \
    aHb = MF(ha[3], bFH[3], aHb);                                                \
    aHa = MF(la[0], bFL[0], aHa);                                                \
    aHb = MF(la[2], bFL[2], aHb);                                                \
    aHa = MF(la[1], bFL[1], aHa);                                                \
    aHb = MF(la[3], bFL[3], aHb);                                                \
    __builtin_amdgcn_s_setprio(0);                                               \
    {                                                                            \
      float fg = sigm_pre(aHa[0] + aHb[0]);                                      \
      float hn = lgf0 + fg * hstate;                                             \
      hstate = hn;                                                               \
      _Float16 hv = (_Float16)hn;                                                \
      *(_Float16*)((char*)(DST) + wr0) = hv;                                     \
      hb0[TIN] = hv;                                                             \
    }                                                                            \
    if ((FLUSH) >= 0)                                                            \
      *(half4_*)((char*)hb40 + (FLUSH)) = hb0;                                   \
    BAR();                                                                       \
  }

  for (int it = 0; it < 32; ++it) {
    STEPX(AhA, AhB, pA, 0, 0, pB, 4096,  0, 0,   -1, 0);
    STEPX(AhB, AhA, pA, 0, 1, pB, 4096, -1, 1,   -1, 0);
    STEPX(AhA, AhB, pA, 1, 0, pB, 4096,  1, 2,   -1, 0);
    STEPX(AhB, AhA, pA, 1, 1, pB, 4096, -1, 3,    0, 0);
    STEPX(AhA, AhB, pA, 2, 0, pB, 4096,  2, 0,   -1, 0);
    STEPX(AhB, AhA, pA, 2, 1, pB, 4096, -1, 1,   -1, 0);
    STEPX(AhA, AhB, pA, 3, 0, pB, 4096,  3, 2,   -1, 0);
    STEPX(AhB, AhA, pA, 3, 1, pB, 4096, -1, 3, 1024, 0);
    STEPX(AhA, AhB, pB, 0, 0, pA, 0,     0, 0,   -1, 1);
    STEPX(AhB, AhA, pB, 0, 1, pA, 0,    -1, 1,   -1, 0);
    STEPX(AhA, AhB, pB, 1, 0, pA, 0,     1, 2,   -1, 0);
    STEPX(AhB, AhA, pB, 1, 1, pA, 0,    -1, 3, 2048, 0);
    STEPX(AhA, AhB, pB, 2, 0, pA, 0,     2, 0,   -1, 0);
    STEPX(AhB, AhA, pB, 2, 1, pA, 0,    -1, 1,   -1, 0);
    STEPX(AhA, AhB, pB, 3, 0, pA, 0,     3, 2,   -1, 0);
    STEPX(AhB, AhA, pB, 3, 1, pA, 0,    -1, 3, 3072, 0);
    hb40 += 2048;
  }
#undef STEPX
}

// ---------------- K6: prediction dot-products (blocked h layout) ----------------
__global__ __launch_bounds__(256) void k6_pred(
    const f16* h_blk, const int* ex_seq, const float* pe,
    const float* W_pred, const float* b_pred, float* out) {
  int tid = threadIdx.x;
  int wv = tid >> 6, lane = tid & 63;
  int task = blockIdx.x * 4 + wv;        // 0..32767
  int br = task >> 7, t4b = task & 127;
  const f16* hp = h_blk + ((size_t)br * 128 + t4b) * 128 * 4;
  half4_ h0 = *(const half4_*)(hp + lane * 4);
  half4_ h1 = *(const half4_*)(hp + (lane + 64) * 4);
  float w0 = W_pred[lane], w1 = W_pred[lane + 64];
  float s[4];
  #pragma unroll
  for (int q = 0; q < 4; q++) s[q] = (float)h0[q] * w0 + (float)h1[q] * w1;
  #pragma unroll
  for (int m = 1; m < 64; m <<= 1) {
    #pragma unroll
    for (int q = 0; q < 4; q++) s[q] += __shfl_xor(s[q], m);
  }
  if (lane == 0) {
    int4 ex = *(const int4*)(ex_seq + (size_t)br * 512 + t4b * 4);
    float bb = b_pred[0];
    float4 o;
    o.x = sigm(s[0] + pe[ex.x] + bb);
    o.y = sigm(s[1] + pe[ex.y] + bb);
    o.z = sigm(s[2] + pe[ex.z] + bb);
    o.w = sigm(s[3] + pe[ex.w] + bb);
    *(float4*)(out + (size_t)br * 512 + t4b * 4) = o;
  }
}

extern "C" void kernel_launch(void* const* d_in, const int* in_sizes, int n_in,
                              void* d_out, int out_size, void* d_ws, size_t ws_size,
                              hipStream_t stream) {
  const int*   ex_seq   = (const int*)d_in[0];
  const int*   sk_seq   = (const int*)d_in[1];
  const int*   re_seq   = (const int*)d_in[2];
  const float* time_seq = (const float*)d_in[3];
  const float* interval_seq = (const float*)d_in[4];
  const float* att_seq  = (const float*)d_in[5];
  const float* hint_seq = (const float*)d_in[6];
  // d_in[7] q_matrix: unused
  const float* ex_emb   = (const float*)d_in[8];
  const float* sk_emb   = (const float*)d_in[9];
  const float* re_emb   = (const float*)d_in[10];
  const float* W_time   = (const float*)d_in[11];
  const float* b_time   = (const float*)d_in[12];
  const float* W_int    = (const float*)d_in[13];
  const float* b_int    = (const float*)d_in[14];
  const float* W_b1     = (const float*)d_in[15];
  const float* b_b1     = (const float*)d_in[16];
  const float* W_b2     = (const float*)d_in[17];
  const float* b_b2     = (const float*)d_in[18];
  const float* W_learn  = (const float*)d_in[19];
  const float* b_learn  = (const float*)d_in[20];
  const float* W_forget = (const float*)d_in[21];
  const float* b_forget = (const float*)d_in[22];
  const float* W_pred   = (const float*)d_in[23];
  const float* b_pred   = (const float*)d_in[24];

  char* ws = (char*)d_ws;
  float* Ee    = (float*)(ws);              // 10,240,000
  float* Se    = (float*)(ws + 10240000);
  float* Re    = (float*)(ws + 10496000);
  float* Te    = (float*)(ws + 10497024);
  float* cbias = (float*)(ws + 10497536);
  float* c_lg  = (float*)(ws + 10498048);
  float* c_fg  = (float*)(ws + 10498560);
  float* fix_l = (float*)(ws + 10499072);
  float* M_lnb = (float*)(ws + 10761728);   // 65,536
  f16*   PRE   = (f16*)  (ws + 10827264);   // 67,108,864  (pair-interleaved PRE2)
  f16*   h_blk = (f16*)  (ws + 77936128);   // 33,554,432 (blocked layout)
  f16*   Wfrag = (f16*)  (ws + 111490560);  // 98,304
  float* pe    = (float*)(ws + 111588864);  // 80,000 -> total 111,668,864
  // aliased scratch:
  f16*   Bfrag = (f16*)  (ws + 77936128);   // aliases h_blk head (dead until k5)

  k1e_Ee<<<dim3(313), dim3(512), 0, stream>>>(ex_emb, W_int, Ee);
  k012_prep<<<dim3(2234), dim3(256), 0, stream>>>(
      ex_emb, sk_emb, re_emb, W_time, b_time, W_int, b_int, W_b2, b_b2,
      W_learn, b_learn, W_forget, b_forget, W_pred,
      Se, Re, Te, cbias, c_lg, c_fg, fix_l, M_lnb, Wfrag, pe, Bfrag);
  k3_gemm_mfma<<<dim3(2048), dim3(512), 0, stream>>>(
      ex_seq, sk_seq, re_seq, time_seq, interval_seq, att_seq, hint_seq,
      W_b1, b_b1, W_learn + 256 * 128, Ee, Se, Re, Te, cbias, c_lg, c_fg, Bfrag, PRE);
  k4_fix<<<dim3(256), dim3(128), 0, stream>>>(
      att_seq, hint_seq, W_b1, b_b1, M_lnb, fix_l, PRE);
  k5_scan_mfma<<<dim3(64), dim3(512), 0, stream>>>(PRE, Wfrag, h_blk);
  k6_pred<<<dim3(8192), dim3(256), 0, stream>>>(
      h_blk, ex_seq, pe, W_pred, b_pred, (float*)d_out);
}